// Round 15
// baseline (162.654 us; speedup 1.0000x reference)
//
#include <hip/hip_runtime.h>
#include <hip/hip_bf16.h>
#include <math.h>

// ---------------------------------------------------------------------------
// HoloKVSimulatorLayer fused pipeline, bf16 MFMA, MI355X (gfx950)
//   B=2 S=2048 H=1024 NH=NKV=16 HD=64 R=16 KF=4 theta=1e6
// R15: attn restructure for 3 blocks/CU: V read direct from L2 (no V LDS,
// 48KB total), unpaired 1024 blocks with LPT+XCD decode. K dbuf + counted
// vmcnt kept. Rest identical to R14.
// ---------------------------------------------------------------------------

typedef __bf16 bf16;
typedef __attribute__((ext_vector_type(8))) __bf16 bf16x8;
typedef __attribute__((ext_vector_type(4))) float f32x4;
typedef __attribute__((ext_vector_type(2))) unsigned u32x2;

#define NB 2
#define SEQ 2048
#define HID 1024
#define NHD 16
#define HDD 64

__device__ __forceinline__ void gld_lds16(const void* g, void* l) {
  __builtin_amdgcn_global_load_lds(
      (const __attribute__((address_space(1))) void*)g,
      (__attribute__((address_space(3))) void*)l, 16, 0, 0);
}

__device__ __forceinline__ unsigned pack2bf(float a, float b) {
  unsigned short ua = __builtin_bit_cast(unsigned short, (bf16)a);
  unsigned short ub = __builtin_bit_cast(unsigned short, (bf16)b);
  return ((unsigned)ub << 16) | ua;
}

// ---------------- P*: all preprocessing, vectorized (4 f32/thread) ---------
#define PB_W    3072
#define PB_HS   (PB_W + 4096)
#define PB_OW   (PB_HS + 1024)
#define PB_BIAS (PB_OW + 12)
#define PB_TAB  (PB_BIAS + 256)

__global__ __launch_bounds__(256) void prep_all(
    const float* __restrict__ hs, const float* __restrict__ ow,
    const float* __restrict__ qw, const float* __restrict__ qb,
    const float* __restrict__ kw, const float* __restrict__ kb,
    const float* __restrict__ vw, const float* __restrict__ vb,
    const float* __restrict__ qA, const float* __restrict__ qB,
    const float* __restrict__ vA, const float* __restrict__ vB,
    bf16* __restrict__ hsb, bf16* __restrict__ owb, bf16* __restrict__ Wqkv,
    float* __restrict__ bqkv, float* __restrict__ ct, float* __restrict__ st) {
  const int bid = blockIdx.x, tid = threadIdx.x;
  if (bid < PB_W) {
    int idx = bid * 256 + tid;           // n*256 + k4idx, n in [0,3072)
    int n = idx >> 8, k4 = (idx & 255) << 2;
    f32x4 v;
    if (n < 1024) {
      v = *(const f32x4*)(qw + (size_t)n * 1024 + k4);
#pragma unroll
      for (int r = 0; r < 16; ++r) {
        float bq = qB[n * 16 + r];
        f32x4 a = *(const f32x4*)(qA + (size_t)r * 1024 + k4);
        v.x += bq * a.x; v.y += bq * a.y; v.z += bq * a.z; v.w += bq * a.w;
      }
    } else if (n < 2048) {
      v = *(const f32x4*)(kw + (size_t)(n - 1024) * 1024 + k4);
    } else {
      int nn = n - 2048;
      v = *(const f32x4*)(vw + (size_t)nn * 1024 + k4);
#pragma unroll
      for (int r = 0; r < 16; ++r) {
        float bv = vB[nn * 16 + r];
        f32x4 a = *(const f32x4*)(vA + (size_t)r * 1024 + k4);
        v.x += bv * a.x; v.y += bv * a.y; v.z += bv * a.z; v.w += bv * a.w;
      }
    }
    int seg = k4 >> 6, cl = k4 & 63;
    int ch = (cl >> 3) ^ (n & 7);
    u32x2 u; u.x = pack2bf(v.x, v.y); u.y = pack2bf(v.z, v.w);
    *(u32x2*)(Wqkv + (size_t)n * 1024 + (seg << 6) + (ch << 3) + (cl & 7)) = u;
  } else if (bid < PB_HS) {
    int idx = (bid - PB_W) * 256 + tid;  // r*256 + c4idx
    int r = idx >> 8, c4 = (idx & 255) << 2;
    f32x4 v = *(const f32x4*)(hs + (size_t)r * 1024 + c4);
    int seg = c4 >> 6, cl = c4 & 63;
    int ch = (cl >> 3) ^ (r & 7);
    u32x2 u; u.x = pack2bf(v.x, v.y); u.y = pack2bf(v.z, v.w);
    *(u32x2*)(hsb + (size_t)r * 1024 + (seg << 6) + (ch << 3) + (cl & 7)) = u;
  } else if (bid < PB_OW) {
    int idx = (bid - PB_HS) * 256 + tid;
    int r = idx >> 8, c4 = (idx & 255) << 2;
    f32x4 v = *(const f32x4*)(ow + (size_t)r * 1024 + c4);
    int seg = c4 >> 6, cl = c4 & 63;
    int ch = (cl >> 3) ^ (r & 7);
    u32x2 u; u.x = pack2bf(v.x, v.y); u.y = pack2bf(v.z, v.w);
    *(u32x2*)(owb + (size_t)r * 1024 + (seg << 6) + (ch << 3) + (cl & 7)) = u;
  } else if (bid < PB_BIAS) {
    int i = (bid - PB_OW) * 256 + tid;
    if (i < 3072)
      bqkv[i] = (i < 1024) ? qb[i] : (i < 2048 ? kb[i - 1024] : vb[i - 2048]);
  } else {
    int idx = (bid - PB_BIAS) * 256 + tid;  // s*32 + i
    int s = idx >> 5, i = idx & 31;
    double inv = pow(1.0e6, -(double)i / 32.0);
    double a = (double)s * inv;
    ct[idx] = (float)cos(a);
    st[idx] = (float)sin(a);
  }
}

// ---------------- K1/K5: bf16 MFMA GEMM, C = A @ Bw^T (+bias) --------------
__global__ __launch_bounds__(256, 4) void gemm_bt(
    const bf16* __restrict__ A, const bf16* __restrict__ Bw,
    const float* __restrict__ bias, bf16* __restrict__ Cb,
    float* __restrict__ Cf, int M, int N, int K) {
  __shared__ __align__(16) bf16 As[128 * 64];
  __shared__ __align__(16) bf16 Bs[128 * 64];
  const int tid = threadIdx.x;
  const int lane = tid & 63, w = tid >> 6;
  const int wm = w >> 1, wn = w & 1;
  const int l15 = lane & 15, l4 = lane >> 4;
  const int m0 = blockIdx.y * 128, n0 = blockIdx.x * 128;
  const size_t rowb = (size_t)K * 2;
  const char* gA = (const char*)A + (size_t)m0 * rowb;
  const char* gB = (const char*)Bw + (size_t)n0 * rowb;
  f32x4 acc[4][4] = {};

  for (int k0 = 0; k0 < K; k0 += 64) {
    const char* gAk = gA + k0 * 2;
    const char* gBk = gB + k0 * 2;
#pragma unroll
    for (int i = 0; i < 4; ++i) {
      int idx = i * 256 + tid;
      int row = idx >> 3, ch = idx & 7;
      gld_lds16(gAk + (size_t)row * rowb + ch * 16,
                (char*)As + (i * 256 + (w << 6)) * 16);
      gld_lds16(gBk + (size_t)row * rowb + ch * 16,
                (char*)Bs + (i * 256 + (w << 6)) * 16);
    }
    __syncthreads();
#pragma unroll
    for (int c = 0; c < 2; ++c) {
      bf16x8 af[4], bfr[4];
#pragma unroll
      for (int mi = 0; mi < 4; ++mi) {
        int row = wm * 64 + mi * 16 + l15;
        int ch = (c * 4 + l4) ^ (row & 7);
        af[mi] = *(const bf16x8*)(As + row * 64 + ch * 8);
      }
#pragma unroll
      for (int ni = 0; ni < 4; ++ni) {
        int row = wn * 64 + ni * 16 + l15;
        int ch = (c * 4 + l4) ^ (row & 7);
        bfr[ni] = *(const bf16x8*)(Bs + row * 64 + ch * 8);
      }
#pragma unroll
      for (int mi = 0; mi < 4; ++mi)
#pragma unroll
        for (int ni = 0; ni < 4; ++ni)
          acc[mi][ni] = __builtin_amdgcn_mfma_f32_16x16x32_bf16(
              af[mi], bfr[ni], acc[mi][ni], 0, 0, 0);
    }
    __syncthreads();
  }
#pragma unroll
  for (int mi = 0; mi < 4; ++mi) {
    int rbase = m0 + wm * 64 + mi * 16 + l4 * 4;
#pragma unroll
    for (int ni = 0; ni < 4; ++ni) {
      int col = n0 + wn * 64 + ni * 16 + l15;
      float badd = bias ? bias[col] : 0.0f;
#pragma unroll
      for (int r = 0; r < 4; ++r) {
        float v = acc[mi][ni][r] + badd;
        if (Cf) Cf[(size_t)(rbase + r) * N + col] = v;
        else    Cb[(size_t)(rbase + r) * N + col] = (bf16)v;
      }
    }
  }
}

// ---------------- K2+K3: RoPE(q) + RoPE(k)/holo, region-dispatched ---------
__global__ __launch_bounds__(256) void rope_holo(
    const bf16* __restrict__ qkv, const int* __restrict__ pos,
    const float* __restrict__ ct, const float* __restrict__ st,
    const float* __restrict__ cdma, bf16* __restrict__ Qr,
    bf16* __restrict__ Kn, bf16* __restrict__ Vt) {
  const int bid = blockIdx.x, tid = threadIdx.x;
  if (bid < 1024) {
    const float SCQ = 0.0901684403f;  // (1/16) * log2(e)
    int idx = bid * 256 + tid;
    int ih = idx & 3, s = (idx >> 2) & 2047, h = (idx >> 13) & 15, b = idx >> 17;
    int p = pos[b * SEQ + s];
    size_t base = ((size_t)(b * SEQ + s)) * 3072 + h * 64 + ih * 8;
    bf16x8 xv = *(const bf16x8*)(qkv + base);
    bf16x8 yv = *(const bf16x8*)(qkv + base + 32);
    const float* ctp = ct + p * 32 + ih * 8;
    const float* stp = st + p * 32 + ih * 8;
    bf16x8 o0, o1;
#pragma unroll
    for (int e = 0; e < 8; ++e) {
      float x = (float)xv[e], y = (float)yv[e];
      float co = ctp[e], sn = stp[e];
      o0[e] = (bf16)((x * co - y * sn) * SCQ);
      o1[e] = (bf16)((y * co + x * sn) * SCQ);
    }
    size_t ob = ((size_t)((b * 16 + h) * SEQ + s)) * 64 + ih * 8;
    *(bf16x8*)(Qr + ob) = o0;
    *(bf16x8*)(Qr + ob + 32) = o1;
  } else {
    int idx = (bid - 1024) * 256 + tid;
    int ih = idx & 3, slot = (idx >> 2) & 511, h = (idx >> 11) & 15, b = idx >> 15;
    float SK[8] = {}, SK2[8] = {}, SV[8] = {}, SV2[8] = {};
#pragma unroll
    for (int f = 0; f < 4; ++f) {
      int s = slot * 4 + f;
      size_t base = ((size_t)(b * SEQ + s)) * 3072 + h * 64 + ih * 8;
      bf16x8 klo = *(const bf16x8*)(qkv + base + 1024);
      bf16x8 khi = *(const bf16x8*)(qkv + base + 1024 + 32);
      bf16x8 vlo = *(const bf16x8*)(qkv + base + 2048);
      bf16x8 vhi = *(const bf16x8*)(qkv + base + 2048 + 32);
      int p = pos[b * SEQ + s];
      const float* ctp = ct + p * 32 + ih * 8;
      const float* stp = st + p * 32 + ih * 8;
      const float* cdp = cdma + f * 64 + ih * 8;
#pragma unroll
      for (int e = 0; e < 8; ++e) {
        float cf = cdp[e];
        float kx = (float)klo[e], ky = (float)khi[e];
        float co = ctp[e], sn = stp[e];
        SK[e]  += (kx * co - ky * sn) * cf;
        SK2[e] += (ky * co + kx * sn) * cf;
        SV[e]  += (float)vlo[e] * cf;
        SV2[e] += (float)vhi[e] * cf;
      }
    }
    size_t hb = (size_t)(b * 16 + h);
#pragma unroll
    for (int f = 0; f < 4; ++f) {
      int s = slot * 4 + f;
      const float* cdp = cdma + f * 64 + ih * 8;
      bf16x8 k0, k1;
#pragma unroll
      for (int e = 0; e < 8; ++e) {
        k0[e] = (bf16)(SK[e] * cdp[e]);
        k1[e] = (bf16)(SK2[e] * cdp[e]);
      }
      size_t krow = (hb * SEQ + s) * 64;
      int ch0 = ih ^ (s & 7);
      int ch1 = (4 + ih) ^ (s & 7);
      *(bf16x8*)(Kn + krow + ch0 * 8) = k0;
      *(bf16x8*)(Kn + krow + ch1 * 8) = k1;
      int seg = s >> 6, cl = s & 63;
      size_t vcol = (size_t)(seg << 6) + (cl & 7);
#pragma unroll
      for (int e = 0; e < 8; ++e) {
        int i = ih * 8 + e;
        int vch = (cl >> 3) ^ (i & 7);
        Vt[(hb * 64 + i) * (size_t)SEQ + vcol + vch * 8] = (bf16)(SV[e] * cdp[e]);
        Vt[(hb * 64 + i + 32) * (size_t)SEQ + vcol + vch * 8] = (bf16)(SV2[e] * cdp[e]);
      }
    }
  }
}

// ---------------- K4: causal flash attention (R15) -------------------------
// 1024 unpaired blocks, LPT + XCD decode: t8=bid>>3; qt=31-(t8>>2) (big
// tiles dispatch first); hb=(bid&7)*4+(t8&3) (4 KV streams per XCD L2).
// K double-buffered in LDS (counted vmcnt); V read DIRECT from pre-swizzled
// global (L2-resident per R13), issued after QK, hidden under softmax.
// LDS 48KB -> 3 blocks/CU.
__global__ __launch_bounds__(256) void attn_fwd(
    const bf16* __restrict__ Qr, const bf16* __restrict__ Kn,
    const bf16* __restrict__ Vt, bf16* __restrict__ AO) {
  __shared__ __align__(16) bf16 Kt[2][128 * 64];   // kv x d, 16KB each
  __shared__ __align__(16) bf16 Pt[4][16 * 128];   // q x kv per wave, 4KB
  const int bid = blockIdx.x;
  const int t8 = bid >> 3;
  const int qt = 31 - (t8 >> 2);
  const int hb = (bid & 7) * 4 + (t8 & 3);
  const int h = hb & 15, b = hb >> 4;
  const int tid = threadIdx.x, lane = tid & 63, w = tid >> 6;
  const int l15 = lane & 15, l4 = lane >> 4;
  const int q0 = qt * 64;
  const int qg = q0 + w * 16 + l15;
  const int nt = (qt >> 1) + 1;
  const size_t hd = ((size_t)(b * 16 + h)) * SEQ * 64;
  const char* gK0 = (const char*)(Kn + hd);
  const char* gV0 = (const char*)(Vt + hd);
  char* pw = (char*)&Pt[w][0];
  const int vswz = (l15 & 7) << 4;

  const bf16* qb = Qr + hd + (size_t)qg * 64;
  bf16x8 qf0 = *(const bf16x8*)(qb + l4 * 8);
  bf16x8 qf1 = *(const bf16x8*)(qb + 32 + l4 * 8);

  f32x4 oacc[4] = {};            // O^T: d = df*16 + l4*4 + r, q = l15
  float m = -1e30f, lsum = 0.0f;

  // prologue: stage K tile 0
#pragma unroll
  for (int i = 0; i < 4; ++i)
    gld_lds16(gK0 + (i * 256 + tid) * 16,
              (char*)Kt[0] + (i * 256 + (w << 6)) * 16);

#pragma unroll 1
  for (int t = 0; t < nt; ++t) {
    const int cur = t & 1;
    if (t + 1 < nt) {
#pragma unroll
      for (int i = 0; i < 4; ++i)
        gld_lds16(gK0 + (size_t)(t + 1) * 16384 + (i * 256 + tid) * 16,
                  (char*)Kt[cur ^ 1] + (i * 256 + (w << 6)) * 16);
      asm volatile("s_waitcnt vmcnt(4)\ns_barrier" ::: "memory");
    } else {
      asm volatile("s_waitcnt vmcnt(0)\ns_barrier" ::: "memory");
    }

    const bf16* Ktc = Kt[cur];
    const int kv0 = t * 128;
    const bool lastt = (t == nt - 1);

    // QK^T swapped (pre-scaled Q): col=l15=q, kv = nf*16 + l4*4 + r
    f32x4 sacc[8] = {};
#pragma unroll
    for (int c = 0; c < 2; ++c) {
      bf16x8 qf = c ? qf1 : qf0;
#pragma unroll
      for (int nf = 0; nf < 8; ++nf) {
        int row = nf * 16 + l15;
        int ch = (c * 4 + l4) ^ (row & 7);
        bf16x8 kf = *(const bf16x8*)(Ktc + row * 64 + ch * 8);
        sacc[nf] = __builtin_amdgcn_mfma_f32_16x16x32_bf16(kf, qf, sacc[nf], 0, 0, 0);
      }
    }

    // issue ALL V loads now (L2-resident); softmax hides the latency
    const char* gVt = gV0 + (size_t)kv0 * 2;
    bf16x8 va[4], vb[4], vc[4], vd[4];
#pragma unroll
    for (int df = 0; df < 4; ++df) {
      const char* rb = gVt + (size_t)(df * 16 + l15) * (SEQ * 2);
      va[df] = *(const bf16x8*)(rb + ((0 * 64 + l4 * 16) ^ vswz));
      vb[df] = *(const bf16x8*)(rb + ((1 * 64 + l4 * 16) ^ vswz));
      vc[df] = *(const bf16x8*)(rb + ((2 * 64 + l4 * 16) ^ vswz));
      vd[df] = *(const bf16x8*)(rb + ((3 * 64 + l4 * 16) ^ vswz));
    }

    // causal mask (last tile only) + 4-acc max tree
    float px[4] = {-1e30f, -1e30f, -1e30f, -1e30f};
    if (lastt) {
#pragma unroll
      for (int nf = 0; nf < 8; ++nf)
#pragma unroll
        for (int r = 0; r < 4; ++r) {
          int kvg = kv0 + nf * 16 + l4 * 4 + r;
          float v = (kvg > qg) ? -1e30f : sacc[nf][r];
          sacc[nf][r] = v;
          px[nf & 3] = fmaxf(px[nf & 3], v);
        }
    } else {
#pragma unroll
      for (int nf = 0; nf < 8; ++nf)
#pragma unroll
        for (int r = 0; r < 4; ++r) px[nf & 3] = fmaxf(px[nf & 3], sacc[nf][r]);
    }
    float pmax = fmaxf(fmaxf(px[0], px[1]), fmaxf(px[2], px[3]));
    pmax = fmaxf(pmax, __shfl_xor(pmax, 16));
    pmax = fmaxf(pmax, __shfl_xor(pmax, 32));

    // online stats; exact skip when no row's max grew
    if (!__all(pmax <= m)) {
      float mn = fmaxf(m, pmax);
      float al = exp2f(m - mn);
      m = mn;
      lsum *= al;
#pragma unroll
      for (int df = 0; df < 4; ++df) oacc[df] *= al;
    }
    float rs4[4] = {0.f, 0.f, 0.f, 0.f};
#pragma unroll
    for (int nf = 0; nf < 8; ++nf)
#pragma unroll
      for (int r = 0; r < 4; ++r) {
        float e = exp2f(sacc[nf][r] - m);
        sacc[nf][r] = e;
        rs4[nf & 3] += e;
      }
    float rs = (rs4[0] + rs4[1]) + (rs4[2] + rs4[3]);
    rs += __shfl_xor(rs, 16);
    rs += __shfl_xor(rs, 32);
    lsum += rs;

    // P (q=l15 row, 256B/row) -> swizzled wave-private LDS, packed b64
#pragma unroll
    for (int nf = 0; nf < 8; ++nf) {
      u32x2 u;
      u.x = pack2bf(sacc[nf][0], sacc[nf][1]);
      u.y = pack2bf(sacc[nf][2], sacc[nf][3]);
      int boff = (l15 * 256 + nf * 32 + l4 * 8) ^ vswz;
      *(u32x2*)(pw + boff) = u;
    }

    // PV swapped: oacc = V^T·P^T over 4 k-slabs of 32, V already in regs
    {
      int pb0 = (l15 * 256 + 0 * 64 + l4 * 16) ^ vswz;
      bf16x8 pf = *(const bf16x8*)(pw + pb0);
#pragma unroll
      for (int df = 0; df < 4; ++df)
        oacc[df] = __builtin_amdgcn_mfma_f32_16x16x32_bf16(va[df], pf, oacc[df], 0, 0, 0);
      int pb1 = (l15 * 256 + 1 * 64 + l4 * 16) ^ vswz;
      pf = *(const bf16x8*)(pw + pb1);
#pragma unroll
      for (int df = 0; df < 4; ++df)
        oacc[df] = __builtin_amdgcn_mfma_f32_16x16x32_bf16(vb[df], pf, oacc[df], 0, 0, 0);
      int pb2 = (l15 * 256 + 2 * 64 + l4 * 16) ^ vswz;
      pf = *(const bf16x8*)(pw + pb2);
#pragma unroll
      for (int df = 0; df < 4; ++df)
        oacc[df] = __builtin_amdgcn_mfma_f32_16x16x32_bf16(vc[df], pf, oacc[df], 0, 0, 0);
      int pb3 = (l15 * 256 + 3 * 64 + l4 * 16) ^ vswz;
      pf = *(const bf16x8*)(pw + pb3);
#pragma unroll
      for (int df = 0; df < 4; ++df)
        oacc[df] = __builtin_amdgcn_mfma_f32_16x16x32_bf16(vd[df], pf, oacc[df], 0, 0, 0);
    }
    asm volatile("s_barrier" ::: "memory");
  }

  // epilogue: O^T -> AO, b64 stores
  const float li = 1.0f / lsum;
  const size_t arow = ((size_t)(b * SEQ + qg)) * HID + h * 64;
  const int qk7 = qg & 7;
#pragma unroll
  for (int df = 0; df < 4; ++df) {
    int ch = (df * 2 + (l4 >> 1)) ^ qk7;
    u32x2 u;
    u.x = pack2bf(oacc[df][0] * li, oacc[df][1] * li);
    u.y = pack2bf(oacc[df][2] * li, oacc[df][3] * li);
    *(u32x2*)(AO + arow + ch * 8 + (l4 & 1) * 4) = u;
  }
}

// ---------------------------------------------------------------------------
extern "C" void kernel_launch(void* const* d_in, const int* in_sizes, int n_in,
                              void* d_out, int out_size, void* d_ws, size_t ws_size,
                              hipStream_t stream) {
  const float* hs  = (const float*)d_in[0];
  const int* pos   = (const int*)d_in[1];
  const float* qw  = (const float*)d_in[2];
  const float* qb_ = (const float*)d_in[3];
  const float* kw  = (const float*)d_in[4];
  const float* kb_ = (const float*)d_in[5];
  const float* vw  = (const float*)d_in[6];
  const float* vb_ = (const float*)d_in[7];
  const float* ow  = (const float*)d_in[8];
  const float* qA  = (const float*)d_in[9];
  const float* qB  = (const float*)d_in[10];
  const float* vA  = (const float*)d_in[11];
  const float* vB  = (const float*)d_in[12];
  const float* cd  = (const float*)d_in[13];

  char* p = (char*)d_ws;
  auto alloc = [&](size_t bytes) {
    char* r = p; p += (bytes + 255) & ~(size_t)255; return r;
  };
  bf16* hsb   = (bf16*)alloc((size_t)4096 * 1024 * 2);
  bf16* Wqkv  = (bf16*)alloc((size_t)3072 * 1024 * 2);
  float* bqkv = (float*)alloc(3072 * 4);
  bf16* owb   = (bf16*)alloc((size_t)1024 * 1024 * 2);
  bf16* qkvb  = (bf16*)alloc((size_t)4096 * 3072 * 2);
  float* ct   = (float*)alloc((size_t)SEQ * 32 * 4);
  float* st   = (float*)alloc((size_t)SEQ * 32 * 4);
  bf16* Qrb   = (bf16*)alloc((size_t)NB * NHD * SEQ * 64 * 2);
  bf16* Knb   = (bf16*)alloc((size_t)NB * NHD * SEQ * 64 * 2);
  bf16* Vtb   = (bf16*)alloc((size_t)NB * NHD * 64 * SEQ * 2);
  bf16* AOb   = (bf16*)alloc((size_t)4096 * 1024 * 2);

  prep_all<<<dim3(PB_TAB), 256, 0, stream>>>(
      hs, ow, qw, qb_, kw, kb_, vw, vb_, qA, qB, vA, vB,
      hsb, owb, Wqkv, bqkv, ct, st);
  gemm_bt<<<dim3(3072 / 128, 4096 / 128), 256, 0, stream>>>(
      hsb, Wqkv, bqkv, qkvb, nullptr, 4096, 3072, 1024);
  rope_holo<<<dim3(1024 + 256), 256, 0, stream>>>(
      qkvb, pos, ct, st, cd, Qrb, Knb, Vtb);
  attn_fwd<<<dim3(1024), 256, 0, stream>>>(Qrb, Knb, Vtb, AOb);
  gemm_bt<<<dim3(1024 / 128, 4096 / 128), 256, 0, stream>>>(
      AOb, owb, nullptr, nullptr, (float*)d_out, 4096, 1024, 1024);
}

// Round 16
// 149.511 us; speedup vs baseline: 1.0879x; 1.0879x over previous
//
#include <hip/hip_runtime.h>
#include <hip/hip_bf16.h>
#include <math.h>

// ---------------------------------------------------------------------------
// HoloKVSimulatorLayer fused pipeline, bf16 MFMA, MI355X (gfx950)
//   B=2 S=2048 H=1024 NH=NKV=16 HD=64 R=16 KF=4 theta=1e6
// R16: revert attn to R14 (paired 512 blocks, V in LDS, XCD swizzle —
// measured best 59.7us; R15's unpair+V-direct regressed to 74us).
// Single delta vs R14: s_setprio(1) around QK/PV MFMA clusters (T5;
// 2 independent-phase blocks/CU = m191-positive regime).
// ---------------------------------------------------------------------------

typedef __bf16 bf16;
typedef __attribute__((ext_vector_type(8))) __bf16 bf16x8;
typedef __attribute__((ext_vector_type(4))) float f32x4;
typedef __attribute__((ext_vector_type(2))) unsigned u32x2;

#define NB 2
#define SEQ 2048
#define HID 1024
#define NHD 16
#define HDD 64

__device__ __forceinline__ void gld_lds16(const void* g, void* l) {
  __builtin_amdgcn_global_load_lds(
      (const __attribute__((address_space(1))) void*)g,
      (__attribute__((address_space(3))) void*)l, 16, 0, 0);
}

__device__ __forceinline__ unsigned pack2bf(float a, float b) {
  unsigned short ua = __builtin_bit_cast(unsigned short, (bf16)a);
  unsigned short ub = __builtin_bit_cast(unsigned short, (bf16)b);
  return ((unsigned)ub << 16) | ua;
}

// ---------------- P*: all preprocessing, vectorized (4 f32/thread) ---------
#define PB_W    3072
#define PB_HS   (PB_W + 4096)
#define PB_OW   (PB_HS + 1024)
#define PB_BIAS (PB_OW + 12)
#define PB_TAB  (PB_BIAS + 256)

__global__ __launch_bounds__(256) void prep_all(
    const float* __restrict__ hs, const float* __restrict__ ow,
    const float* __restrict__ qw, const float* __restrict__ qb,
    const float* __restrict__ kw, const float* __restrict__ kb,
    const float* __restrict__ vw, const float* __restrict__ vb,
    const float* __restrict__ qA, const float* __restrict__ qB,
    const float* __restrict__ vA, const float* __restrict__ vB,
    bf16* __restrict__ hsb, bf16* __restrict__ owb, bf16* __restrict__ Wqkv,
    float* __restrict__ bqkv, float* __restrict__ ct, float* __restrict__ st) {
  const int bid = blockIdx.x, tid = threadIdx.x;
  if (bid < PB_W) {
    int idx = bid * 256 + tid;           // n*256 + k4idx, n in [0,3072)
    int n = idx >> 8, k4 = (idx & 255) << 2;
    f32x4 v;
    if (n < 1024) {
      v = *(const f32x4*)(qw + (size_t)n * 1024 + k4);
#pragma unroll
      for (int r = 0; r < 16; ++r) {
        float bq = qB[n * 16 + r];
        f32x4 a = *(const f32x4*)(qA + (size_t)r * 1024 + k4);
        v.x += bq * a.x; v.y += bq * a.y; v.z += bq * a.z; v.w += bq * a.w;
      }
    } else if (n < 2048) {
      v = *(const f32x4*)(kw + (size_t)(n - 1024) * 1024 + k4);
    } else {
      int nn = n - 2048;
      v = *(const f32x4*)(vw + (size_t)nn * 1024 + k4);
#pragma unroll
      for (int r = 0; r < 16; ++r) {
        float bv = vB[nn * 16 + r];
        f32x4 a = *(const f32x4*)(vA + (size_t)r * 1024 + k4);
        v.x += bv * a.x; v.y += bv * a.y; v.z += bv * a.z; v.w += bv * a.w;
      }
    }
    int seg = k4 >> 6, cl = k4 & 63;
    int ch = (cl >> 3) ^ (n & 7);
    u32x2 u; u.x = pack2bf(v.x, v.y); u.y = pack2bf(v.z, v.w);
    *(u32x2*)(Wqkv + (size_t)n * 1024 + (seg << 6) + (ch << 3) + (cl & 7)) = u;
  } else if (bid < PB_HS) {
    int idx = (bid - PB_W) * 256 + tid;  // r*256 + c4idx
    int r = idx >> 8, c4 = (idx & 255) << 2;
    f32x4 v = *(const f32x4*)(hs + (size_t)r * 1024 + c4);
    int seg = c4 >> 6, cl = c4 & 63;
    int ch = (cl >> 3) ^ (r & 7);
    u32x2 u; u.x = pack2bf(v.x, v.y); u.y = pack2bf(v.z, v.w);
    *(u32x2*)(hsb + (size_t)r * 1024 + (seg << 6) + (ch << 3) + (cl & 7)) = u;
  } else if (bid < PB_OW) {
    int idx = (bid - PB_HS) * 256 + tid;
    int r = idx >> 8, c4 = (idx & 255) << 2;
    f32x4 v = *(const f32x4*)(ow + (size_t)r * 1024 + c4);
    int seg = c4 >> 6, cl = c4 & 63;
    int ch = (cl >> 3) ^ (r & 7);
    u32x2 u; u.x = pack2bf(v.x, v.y); u.y = pack2bf(v.z, v.w);
    *(u32x2*)(owb + (size_t)r * 1024 + (seg << 6) + (ch << 3) + (cl & 7)) = u;
  } else if (bid < PB_BIAS) {
    int i = (bid - PB_OW) * 256 + tid;
    if (i < 3072)
      bqkv[i] = (i < 1024) ? qb[i] : (i < 2048 ? kb[i - 1024] : vb[i - 2048]);
  } else {
    int idx = (bid - PB_BIAS) * 256 + tid;  // s*32 + i
    int s = idx >> 5, i = idx & 31;
    double inv = pow(1.0e6, -(double)i / 32.0);
    double a = (double)s * inv;
    ct[idx] = (float)cos(a);
    st[idx] = (float)sin(a);
  }
}

// ---------------- K1/K5: bf16 MFMA GEMM, C = A @ Bw^T (+bias) --------------
__global__ __launch_bounds__(256, 4) void gemm_bt(
    const bf16* __restrict__ A, const bf16* __restrict__ Bw,
    const float* __restrict__ bias, bf16* __restrict__ Cb,
    float* __restrict__ Cf, int M, int N, int K) {
  __shared__ __align__(16) bf16 As[128 * 64];
  __shared__ __align__(16) bf16 Bs[128 * 64];
  const int tid = threadIdx.x;
  const int lane = tid & 63, w = tid >> 6;
  const int wm = w >> 1, wn = w & 1;
  const int l15 = lane & 15, l4 = lane >> 4;
  const int m0 = blockIdx.y * 128, n0 = blockIdx.x * 128;
  const size_t rowb = (size_t)K * 2;
  const char* gA = (const char*)A + (size_t)m0 * rowb;
  const char* gB = (const char*)Bw + (size_t)n0 * rowb;
  f32x4 acc[4][4] = {};

  for (int k0 = 0; k0 < K; k0 += 64) {
    const char* gAk = gA + k0 * 2;
    const char* gBk = gB + k0 * 2;
#pragma unroll
    for (int i = 0; i < 4; ++i) {
      int idx = i * 256 + tid;
      int row = idx >> 3, ch = idx & 7;
      gld_lds16(gAk + (size_t)row * rowb + ch * 16,
                (char*)As + (i * 256 + (w << 6)) * 16);
      gld_lds16(gBk + (size_t)row * rowb + ch * 16,
                (char*)Bs + (i * 256 + (w << 6)) * 16);
    }
    __syncthreads();
#pragma unroll
    for (int c = 0; c < 2; ++c) {
      bf16x8 af[4], bfr[4];
#pragma unroll
      for (int mi = 0; mi < 4; ++mi) {
        int row = wm * 64 + mi * 16 + l15;
        int ch = (c * 4 + l4) ^ (row & 7);
        af[mi] = *(const bf16x8*)(As + row * 64 + ch * 8);
      }
#pragma unroll
      for (int ni = 0; ni < 4; ++ni) {
        int row = wn * 64 + ni * 16 + l15;
        int ch = (c * 4 + l4) ^ (row & 7);
        bfr[ni] = *(const bf16x8*)(Bs + row * 64 + ch * 8);
      }
#pragma unroll
      for (int mi = 0; mi < 4; ++mi)
#pragma unroll
        for (int ni = 0; ni < 4; ++ni)
          acc[mi][ni] = __builtin_amdgcn_mfma_f32_16x16x32_bf16(
              af[mi], bfr[ni], acc[mi][ni], 0, 0, 0);
    }
    __syncthreads();
  }
#pragma unroll
  for (int mi = 0; mi < 4; ++mi) {
    int rbase = m0 + wm * 64 + mi * 16 + l4 * 4;
#pragma unroll
    for (int ni = 0; ni < 4; ++ni) {
      int col = n0 + wn * 64 + ni * 16 + l15;
      float badd = bias ? bias[col] : 0.0f;
#pragma unroll
      for (int r = 0; r < 4; ++r) {
        float v = acc[mi][ni][r] + badd;
        if (Cf) Cf[(size_t)(rbase + r) * N + col] = v;
        else    Cb[(size_t)(rbase + r) * N + col] = (bf16)v;
      }
    }
  }
}

// ---------------- K2+K3: RoPE(q) + RoPE(k)/holo, region-dispatched ---------
__global__ __launch_bounds__(256) void rope_holo(
    const bf16* __restrict__ qkv, const int* __restrict__ pos,
    const float* __restrict__ ct, const float* __restrict__ st,
    const float* __restrict__ cdma, bf16* __restrict__ Qr,
    bf16* __restrict__ Kn, bf16* __restrict__ Vt) {
  const int bid = blockIdx.x, tid = threadIdx.x;
  if (bid < 1024) {
    const float SCQ = 0.0901684403f;  // (1/16) * log2(e)
    int idx = bid * 256 + tid;
    int ih = idx & 3, s = (idx >> 2) & 2047, h = (idx >> 13) & 15, b = idx >> 17;
    int p = pos[b * SEQ + s];
    size_t base = ((size_t)(b * SEQ + s)) * 3072 + h * 64 + ih * 8;
    bf16x8 xv = *(const bf16x8*)(qkv + base);
    bf16x8 yv = *(const bf16x8*)(qkv + base + 32);
    const float* ctp = ct + p * 32 + ih * 8;
    const float* stp = st + p * 32 + ih * 8;
    bf16x8 o0, o1;
#pragma unroll
    for (int e = 0; e < 8; ++e) {
      float x = (float)xv[e], y = (float)yv[e];
      float co = ctp[e], sn = stp[e];
      o0[e] = (bf16)((x * co - y * sn) * SCQ);
      o1[e] = (bf16)((y * co + x * sn) * SCQ);
    }
    size_t ob = ((size_t)((b * 16 + h) * SEQ + s)) * 64 + ih * 8;
    *(bf16x8*)(Qr + ob) = o0;
    *(bf16x8*)(Qr + ob + 32) = o1;
  } else {
    int idx = (bid - 1024) * 256 + tid;
    int ih = idx & 3, slot = (idx >> 2) & 511, h = (idx >> 11) & 15, b = idx >> 15;
    float SK[8] = {}, SK2[8] = {}, SV[8] = {}, SV2[8] = {};
#pragma unroll
    for (int f = 0; f < 4; ++f) {
      int s = slot * 4 + f;
      size_t base = ((size_t)(b * SEQ + s)) * 3072 + h * 64 + ih * 8;
      bf16x8 klo = *(const bf16x8*)(qkv + base + 1024);
      bf16x8 khi = *(const bf16x8*)(qkv + base + 1024 + 32);
      bf16x8 vlo = *(const bf16x8*)(qkv + base + 2048);
      bf16x8 vhi = *(const bf16x8*)(qkv + base + 2048 + 32);
      int p = pos[b * SEQ + s];
      const float* ctp = ct + p * 32 + ih * 8;
      const float* stp = st + p * 32 + ih * 8;
      const float* cdp = cdma + f * 64 + ih * 8;
#pragma unroll
      for (int e = 0; e < 8; ++e) {
        float cf = cdp[e];
        float kx = (float)klo[e], ky = (float)khi[e];
        float co = ctp[e], sn = stp[e];
        SK[e]  += (kx * co - ky * sn) * cf;
        SK2[e] += (ky * co + kx * sn) * cf;
        SV[e]  += (float)vlo[e] * cf;
        SV2[e] += (float)vhi[e] * cf;
      }
    }
    size_t hb = (size_t)(b * 16 + h);
#pragma unroll
    for (int f = 0; f < 4; ++f) {
      int s = slot * 4 + f;
      const float* cdp = cdma + f * 64 + ih * 8;
      bf16x8 k0, k1;
#pragma unroll
      for (int e = 0; e < 8; ++e) {
        k0[e] = (bf16)(SK[e] * cdp[e]);
        k1[e] = (bf16)(SK2[e] * cdp[e]);
      }
      size_t krow = (hb * SEQ + s) * 64;
      int ch0 = ih ^ (s & 7);
      int ch1 = (4 + ih) ^ (s & 7);
      *(bf16x8*)(Kn + krow + ch0 * 8) = k0;
      *(bf16x8*)(Kn + krow + ch1 * 8) = k1;
      int seg = s >> 6, cl = s & 63;
      size_t vcol = (size_t)(seg << 6) + (cl & 7);
#pragma unroll
      for (int e = 0; e < 8; ++e) {
        int i = ih * 8 + e;
        int vch = (cl >> 3) ^ (i & 7);
        Vt[(hb * 64 + i) * (size_t)SEQ + vcol + vch * 8] = (bf16)(SV[e] * cdp[e]);
        Vt[(hb * 64 + i + 32) * (size_t)SEQ + vcol + vch * 8] = (bf16)(SV2[e] * cdp[e]);
      }
    }
  }
}

// ---------------- K4: causal flash attention (R14 + setprio) ---------------
__global__ __launch_bounds__(256) void attn_fwd(
    const bf16* __restrict__ Qr, const bf16* __restrict__ Kn,
    const bf16* __restrict__ Vt, bf16* __restrict__ AO) {
  __shared__ __align__(16) bf16 Kt[2][128 * 64];
  __shared__ __align__(16) bf16 Vl[2][64 * 128];
  __shared__ __align__(16) bf16 Pt[4][16 * 128];
  const int L = ((blockIdx.x & 7) << 6) + (blockIdx.x >> 3);
  const int pq = L & 15, h = (L >> 4) & 15, b = L >> 8;
  const int tid = threadIdx.x, lane = tid & 63, w = tid >> 6;
  const int l15 = lane & 15, l4 = lane >> 4;
  const size_t hd = ((size_t)(b * 16 + h)) * SEQ * 64;
  const char* gK0 = (const char*)(Kn + hd);
  const char* gV0 = (const char*)(Vt + hd);
  char* pw = (char*)&Pt[w][0];

#pragma unroll 1
  for (int phase = 0; phase < 2; ++phase) {
    const int qt = phase ? (31 - pq) : pq;
    const int q0 = qt * 64;
    const int qg = q0 + w * 16 + l15;
    const int nt = (qt >> 1) + 1;

    const bf16* qb = Qr + hd + (size_t)qg * 64;
    bf16x8 qf0 = *(const bf16x8*)(qb + l4 * 8);
    bf16x8 qf1 = *(const bf16x8*)(qb + 32 + l4 * 8);

    f32x4 oacc[4] = {};
    float m = -1e30f, lsum = 0.0f;

#pragma unroll
    for (int i = 0; i < 4; ++i)
      gld_lds16(gK0 + (i * 256 + tid) * 16,
                (char*)Kt[0] + (i * 256 + (w << 6)) * 16);
#pragma unroll
    for (int i = 0; i < 4; ++i) {
      int idx = i * 256 + tid;
      int row = idx >> 4, ch = idx & 15;
      gld_lds16(gV0 + (size_t)row * (SEQ * 2) + ch * 16,
                (char*)Vl[0] + (i * 256 + (w << 6)) * 16);
    }

#pragma unroll 1
    for (int t = 0; t < nt; ++t) {
      const int cur = t & 1;
      if (t + 1 < nt) {
        const int tn = t + 1, sb = cur ^ 1;
#pragma unroll
        for (int i = 0; i < 4; ++i)
          gld_lds16(gK0 + (size_t)tn * 16384 + (i * 256 + tid) * 16,
                    (char*)Kt[sb] + (i * 256 + (w << 6)) * 16);
#pragma unroll
        for (int i = 0; i < 4; ++i) {
          int idx = i * 256 + tid;
          int row = idx >> 4, ch = idx & 15;
          gld_lds16(gV0 + (size_t)row * (SEQ * 2) + tn * 256 + ch * 16,
                    (char*)Vl[sb] + (i * 256 + (w << 6)) * 16);
        }
        asm volatile("s_waitcnt vmcnt(8)\ns_barrier" ::: "memory");
      } else {
        asm volatile("s_waitcnt vmcnt(0)\ns_barrier" ::: "memory");
      }

      const bf16* Ktc = Kt[cur];
      const bf16* Vlc = Vl[cur];
      const int kv0 = t * 128;
      const bool lastt = (t == nt - 1);

      f32x4 sacc[8] = {};
      __builtin_amdgcn_s_setprio(1);
#pragma unroll
      for (int c = 0; c < 2; ++c) {
        bf16x8 qf = c ? qf1 : qf0;
#pragma unroll
        for (int nf = 0; nf < 8; ++nf) {
          int row = nf * 16 + l15;
          int ch = (c * 4 + l4) ^ (row & 7);
          bf16x8 kf = *(const bf16x8*)(Ktc + row * 64 + ch * 8);
          sacc[nf] = __builtin_amdgcn_mfma_f32_16x16x32_bf16(kf, qf, sacc[nf], 0, 0, 0);
        }
      }
      __builtin_amdgcn_s_setprio(0);

      float px[4] = {-1e30f, -1e30f, -1e30f, -1e30f};
      if (lastt) {
#pragma unroll
        for (int nf = 0; nf < 8; ++nf)
#pragma unroll
          for (int r = 0; r < 4; ++r) {
            int kvg = kv0 + nf * 16 + l4 * 4 + r;
            float v = (kvg > qg) ? -1e30f : sacc[nf][r];
            sacc[nf][r] = v;
            px[nf & 3] = fmaxf(px[nf & 3], v);
          }
      } else {
#pragma unroll
        for (int nf = 0; nf < 8; ++nf)
#pragma unroll
          for (int r = 0; r < 4; ++r) px[nf & 3] = fmaxf(px[nf & 3], sacc[nf][r]);
      }
      float pmax = fmaxf(fmaxf(px[0], px[1]), fmaxf(px[2], px[3]));
      pmax = fmaxf(pmax, __shfl_xor(pmax, 16));
      pmax = fmaxf(pmax, __shfl_xor(pmax, 32));

      if (!__all(pmax <= m)) {
        float mn = fmaxf(m, pmax);
        float al = exp2f(m - mn);
        m = mn;
        lsum *= al;
#pragma unroll
        for (int df = 0; df < 4; ++df) oacc[df] *= al;
      }
      float rs4[4] = {0.f, 0.f, 0.f, 0.f};
#pragma unroll
      for (int nf = 0; nf < 8; ++nf)
#pragma unroll
        for (int r = 0; r < 4; ++r) {
          float e = exp2f(sacc[nf][r] - m);
          sacc[nf][r] = e;
          rs4[nf & 3] += e;
        }
      float rs = (rs4[0] + rs4[1]) + (rs4[2] + rs4[3]);
      rs += __shfl_xor(rs, 16);
      rs += __shfl_xor(rs, 32);
      lsum += rs;

#pragma unroll
      for (int nf = 0; nf < 8; ++nf) {
        u32x2 u;
        u.x = pack2bf(sacc[nf][0], sacc[nf][1]);
        u.y = pack2bf(sacc[nf][2], sacc[nf][3]);
        int boff = (l15 * 256 + nf * 32 + l4 * 8) ^ ((l15 & 7) << 4);
        *(u32x2*)(pw + boff) = u;
      }

      __builtin_amdgcn_s_setprio(1);
#pragma unroll
      for (int c2 = 0; c2 < 4; ++c2) {
        int pb = (l15 * 256 + c2 * 64 + l4 * 16) ^ ((l15 & 7) << 4);
        bf16x8 pf = *(const bf16x8*)(pw + pb);
        int vbyte = (c2 * 64 + l4 * 16) ^ ((l15 & 7) << 4);
#pragma unroll
        for (int df = 0; df < 4; ++df) {
          int vrow = df * 16 + l15;
          bf16x8 vf = *(const bf16x8*)((const char*)Vlc + vrow * 256 + vbyte);
          oacc[df] = __builtin_amdgcn_mfma_f32_16x16x32_bf16(vf, pf, oacc[df], 0, 0, 0);
        }
      }
      __builtin_amdgcn_s_setprio(0);
      asm volatile("s_barrier" ::: "memory");
    }

    // epilogue: O^T -> AO, b64 stores (d>>3 constant across r; d&7=(l4&1)*4+r)
    const float li = 1.0f / lsum;
    const size_t arow = ((size_t)(b * SEQ + qg)) * HID + h * 64;
    const int qk7 = qg & 7;
#pragma unroll
    for (int df = 0; df < 4; ++df) {
      int ch = (df * 2 + (l4 >> 1)) ^ qk7;
      u32x2 u;
      u.x = pack2bf(oacc[df][0] * li, oacc[df][1] * li);
      u.y = pack2bf(oacc[df][2] * li, oacc[df][3] * li);
      *(u32x2*)(AO + arow + ch * 8 + (l4 & 1) * 4) = u;
    }
  }
}

// ---------------------------------------------------------------------------
extern "C" void kernel_launch(void* const* d_in, const int* in_sizes, int n_in,
                              void* d_out, int out_size, void* d_ws, size_t ws_size,
                              hipStream_t stream) {
  const float* hs  = (const float*)d_in[0];
  const int* pos   = (const int*)d_in[1];
  const float* qw  = (const float*)d_in[2];
  const float* qb_ = (const float*)d_in[3];
  const float* kw  = (const float*)d_in[4];
  const float* kb_ = (const float*)d_in[5];
  const float* vw  = (const float*)d_in[6];
  const float* vb_ = (const float*)d_in[7];
  const float* ow  = (const float*)d_in[8];
  const float* qA  = (const float*)d_in[9];
  const float* qB  = (const float*)d_in[10];
  const float* vA  = (const float*)d_in[11];
  const float* vB  = (const float*)d_in[12];
  const float* cd  = (const float*)d_in[13];

  char* p = (char*)d_ws;
  auto alloc = [&](size_t bytes) {
    char* r = p; p += (bytes + 255) & ~(size_t)255; return r;
  };
  bf16* hsb   = (bf16*)alloc((size_t)4096 * 1024 * 2);
  bf16* Wqkv  = (bf16*)alloc((size_t)3072 * 1024 * 2);
  float* bqkv = (float*)alloc(3072 * 4);
  bf16* owb   = (bf16*)alloc((size_t)1024 * 1024 * 2);
  bf16* qkvb  = (bf16*)alloc((size_t)4096 * 3072 * 2);
  float* ct   = (float*)alloc((size_t)SEQ * 32 * 4);
  float* st   = (float*)alloc((size_t)SEQ * 32 * 4);
  bf16* Qrb   = (bf16*)alloc((size_t)NB * NHD * SEQ * 64 * 2);
  bf16* Knb   = (bf16*)alloc((size_t)NB * NHD * SEQ * 64 * 2);
  bf16* Vtb   = (bf16*)alloc((size_t)NB * NHD * 64 * SEQ * 2);
  bf16* AOb   = (bf16*)alloc((size_t)4096 * 1024 * 2);

  prep_all<<<dim3(PB_TAB), 256, 0, stream>>>(
      hs, ow, qw, qb_, kw, kb_, vw, vb_, qA, qB, vA, vB,
      hsb, owb, Wqkv, bqkv, ct, st);
  gemm_bt<<<dim3(3072 / 128, 4096 / 128), 256, 0, stream>>>(
      hsb, Wqkv, bqkv, qkvb, nullptr, 4096, 3072, 1024);
  rope_holo<<<dim3(1024 + 256), 256, 0, stream>>>(
      qkvb, pos, ct, st, cd, Qrb, Knb, Vtb);
  attn_fwd<<<dim3(512), 256, 0, stream>>>(Qrb, Knb, Vtb, AOb);
  gemm_bt<<<dim3(1024 / 128, 4096 / 128), 256, 0, stream>>>(
      AOb, owb, nullptr, nullptr, (float*)d_out, 4096, 1024, 1024);
}

// Round 17
// 144.487 us; speedup vs baseline: 1.1257x; 1.0348x over previous
//
#include <hip/hip_runtime.h>
#include <hip/hip_bf16.h>
#include <math.h>

// ---------------------------------------------------------------------------
// HoloKVSimulatorLayer fused pipeline, bf16 MFMA, MI355X (gfx950)
//   B=2 S=2048 H=1024 NH=NKV=16 HD=64 R=16 KF=4 theta=1e6
// R17: attn = R14-exact (setprio removed; R16 showed neutral-negative).
// New gemm_bt_n64 (BM=128,BN=64) for the output GEMM: grid 512 blocks =
// 2/CU (was 256 = 1/CU, zero overlap). gemm1 unchanged 128^2.
// ---------------------------------------------------------------------------

typedef __bf16 bf16;
typedef __attribute__((ext_vector_type(8))) __bf16 bf16x8;
typedef __attribute__((ext_vector_type(4))) float f32x4;
typedef __attribute__((ext_vector_type(2))) unsigned u32x2;

#define NB 2
#define SEQ 2048
#define HID 1024
#define NHD 16
#define HDD 64

__device__ __forceinline__ void gld_lds16(const void* g, void* l) {
  __builtin_amdgcn_global_load_lds(
      (const __attribute__((address_space(1))) void*)g,
      (__attribute__((address_space(3))) void*)l, 16, 0, 0);
}

__device__ __forceinline__ unsigned pack2bf(float a, float b) {
  unsigned short ua = __builtin_bit_cast(unsigned short, (bf16)a);
  unsigned short ub = __builtin_bit_cast(unsigned short, (bf16)b);
  return ((unsigned)ub << 16) | ua;
}

// ---------------- P*: all preprocessing, vectorized (4 f32/thread) ---------
#define PB_W    3072
#define PB_HS   (PB_W + 4096)
#define PB_OW   (PB_HS + 1024)
#define PB_BIAS (PB_OW + 12)
#define PB_TAB  (PB_BIAS + 256)

__global__ __launch_bounds__(256) void prep_all(
    const float* __restrict__ hs, const float* __restrict__ ow,
    const float* __restrict__ qw, const float* __restrict__ qb,
    const float* __restrict__ kw, const float* __restrict__ kb,
    const float* __restrict__ vw, const float* __restrict__ vb,
    const float* __restrict__ qA, const float* __restrict__ qB,
    const float* __restrict__ vA, const float* __restrict__ vB,
    bf16* __restrict__ hsb, bf16* __restrict__ owb, bf16* __restrict__ Wqkv,
    float* __restrict__ bqkv, float* __restrict__ ct, float* __restrict__ st) {
  const int bid = blockIdx.x, tid = threadIdx.x;
  if (bid < PB_W) {
    int idx = bid * 256 + tid;           // n*256 + k4idx, n in [0,3072)
    int n = idx >> 8, k4 = (idx & 255) << 2;
    f32x4 v;
    if (n < 1024) {
      v = *(const f32x4*)(qw + (size_t)n * 1024 + k4);
#pragma unroll
      for (int r = 0; r < 16; ++r) {
        float bq = qB[n * 16 + r];
        f32x4 a = *(const f32x4*)(qA + (size_t)r * 1024 + k4);
        v.x += bq * a.x; v.y += bq * a.y; v.z += bq * a.z; v.w += bq * a.w;
      }
    } else if (n < 2048) {
      v = *(const f32x4*)(kw + (size_t)(n - 1024) * 1024 + k4);
    } else {
      int nn = n - 2048;
      v = *(const f32x4*)(vw + (size_t)nn * 1024 + k4);
#pragma unroll
      for (int r = 0; r < 16; ++r) {
        float bv = vB[nn * 16 + r];
        f32x4 a = *(const f32x4*)(vA + (size_t)r * 1024 + k4);
        v.x += bv * a.x; v.y += bv * a.y; v.z += bv * a.z; v.w += bv * a.w;
      }
    }
    int seg = k4 >> 6, cl = k4 & 63;
    int ch = (cl >> 3) ^ (n & 7);
    u32x2 u; u.x = pack2bf(v.x, v.y); u.y = pack2bf(v.z, v.w);
    *(u32x2*)(Wqkv + (size_t)n * 1024 + (seg << 6) + (ch << 3) + (cl & 7)) = u;
  } else if (bid < PB_HS) {
    int idx = (bid - PB_W) * 256 + tid;  // r*256 + c4idx
    int r = idx >> 8, c4 = (idx & 255) << 2;
    f32x4 v = *(const f32x4*)(hs + (size_t)r * 1024 + c4);
    int seg = c4 >> 6, cl = c4 & 63;
    int ch = (cl >> 3) ^ (r & 7);
    u32x2 u; u.x = pack2bf(v.x, v.y); u.y = pack2bf(v.z, v.w);
    *(u32x2*)(hsb + (size_t)r * 1024 + (seg << 6) + (ch << 3) + (cl & 7)) = u;
  } else if (bid < PB_OW) {
    int idx = (bid - PB_HS) * 256 + tid;
    int r = idx >> 8, c4 = (idx & 255) << 2;
    f32x4 v = *(const f32x4*)(ow + (size_t)r * 1024 + c4);
    int seg = c4 >> 6, cl = c4 & 63;
    int ch = (cl >> 3) ^ (r & 7);
    u32x2 u; u.x = pack2bf(v.x, v.y); u.y = pack2bf(v.z, v.w);
    *(u32x2*)(owb + (size_t)r * 1024 + (seg << 6) + (ch << 3) + (cl & 7)) = u;
  } else if (bid < PB_BIAS) {
    int i = (bid - PB_OW) * 256 + tid;
    if (i < 3072)
      bqkv[i] = (i < 1024) ? qb[i] : (i < 2048 ? kb[i - 1024] : vb[i - 2048]);
  } else {
    int idx = (bid - PB_BIAS) * 256 + tid;  // s*32 + i
    int s = idx >> 5, i = idx & 31;
    double inv = pow(1.0e6, -(double)i / 32.0);
    double a = (double)s * inv;
    ct[idx] = (float)cos(a);
    st[idx] = (float)sin(a);
  }
}

// ---------------- K1: bf16 MFMA GEMM 128x128, C = A @ Bw^T (+bias) ---------
__global__ __launch_bounds__(256, 4) void gemm_bt(
    const bf16* __restrict__ A, const bf16* __restrict__ Bw,
    const float* __restrict__ bias, bf16* __restrict__ Cb,
    float* __restrict__ Cf, int M, int N, int K) {
  __shared__ __align__(16) bf16 As[128 * 64];
  __shared__ __align__(16) bf16 Bs[128 * 64];
  const int tid = threadIdx.x;
  const int lane = tid & 63, w = tid >> 6;
  const int wm = w >> 1, wn = w & 1;
  const int l15 = lane & 15, l4 = lane >> 4;
  const int m0 = blockIdx.y * 128, n0 = blockIdx.x * 128;
  const size_t rowb = (size_t)K * 2;
  const char* gA = (const char*)A + (size_t)m0 * rowb;
  const char* gB = (const char*)Bw + (size_t)n0 * rowb;
  f32x4 acc[4][4] = {};

  for (int k0 = 0; k0 < K; k0 += 64) {
    const char* gAk = gA + k0 * 2;
    const char* gBk = gB + k0 * 2;
#pragma unroll
    for (int i = 0; i < 4; ++i) {
      int idx = i * 256 + tid;
      int row = idx >> 3, ch = idx & 7;
      gld_lds16(gAk + (size_t)row * rowb + ch * 16,
                (char*)As + (i * 256 + (w << 6)) * 16);
      gld_lds16(gBk + (size_t)row * rowb + ch * 16,
                (char*)Bs + (i * 256 + (w << 6)) * 16);
    }
    __syncthreads();
#pragma unroll
    for (int c = 0; c < 2; ++c) {
      bf16x8 af[4], bfr[4];
#pragma unroll
      for (int mi = 0; mi < 4; ++mi) {
        int row = wm * 64 + mi * 16 + l15;
        int ch = (c * 4 + l4) ^ (row & 7);
        af[mi] = *(const bf16x8*)(As + row * 64 + ch * 8);
      }
#pragma unroll
      for (int ni = 0; ni < 4; ++ni) {
        int row = wn * 64 + ni * 16 + l15;
        int ch = (c * 4 + l4) ^ (row & 7);
        bfr[ni] = *(const bf16x8*)(Bs + row * 64 + ch * 8);
      }
#pragma unroll
      for (int mi = 0; mi < 4; ++mi)
#pragma unroll
        for (int ni = 0; ni < 4; ++ni)
          acc[mi][ni] = __builtin_amdgcn_mfma_f32_16x16x32_bf16(
              af[mi], bfr[ni], acc[mi][ni], 0, 0, 0);
    }
    __syncthreads();
  }
#pragma unroll
  for (int mi = 0; mi < 4; ++mi) {
    int rbase = m0 + wm * 64 + mi * 16 + l4 * 4;
#pragma unroll
    for (int ni = 0; ni < 4; ++ni) {
      int col = n0 + wn * 64 + ni * 16 + l15;
      float badd = bias ? bias[col] : 0.0f;
#pragma unroll
      for (int r = 0; r < 4; ++r) {
        float v = acc[mi][ni][r] + badd;
        if (Cf) Cf[(size_t)(rbase + r) * N + col] = v;
        else    Cb[(size_t)(rbase + r) * N + col] = (bf16)v;
      }
    }
  }
}

// ---------------- K5: bf16 MFMA GEMM 128x64 (f32 out), 2 blocks/CU ---------
// For the output GEMM (N=1024): grid (16,32)=512 blocks = 2/CU overlap.
// Wave tile 64x32 (acc[4][2]); Bs is 64x64.
__global__ __launch_bounds__(256, 4) void gemm_bt_n64(
    const bf16* __restrict__ A, const bf16* __restrict__ Bw,
    float* __restrict__ Cf, int M, int N, int K) {
  __shared__ __align__(16) bf16 As[128 * 64];
  __shared__ __align__(16) bf16 Bs[64 * 64];
  const int tid = threadIdx.x;
  const int lane = tid & 63, w = tid >> 6;
  const int wm = w >> 1, wn = w & 1;
  const int l15 = lane & 15, l4 = lane >> 4;
  const int m0 = blockIdx.y * 128, n0 = blockIdx.x * 64;
  const size_t rowb = (size_t)K * 2;
  const char* gA = (const char*)A + (size_t)m0 * rowb;
  const char* gB = (const char*)Bw + (size_t)n0 * rowb;
  f32x4 acc[4][2] = {};

  for (int k0 = 0; k0 < K; k0 += 64) {
    const char* gAk = gA + k0 * 2;
    const char* gBk = gB + k0 * 2;
#pragma unroll
    for (int i = 0; i < 4; ++i) {
      int idx = i * 256 + tid;
      int row = idx >> 3, ch = idx & 7;
      gld_lds16(gAk + (size_t)row * rowb + ch * 16,
                (char*)As + (i * 256 + (w << 6)) * 16);
    }
#pragma unroll
    for (int i = 0; i < 2; ++i) {
      int idx = i * 256 + tid;
      int row = idx >> 3, ch = idx & 7;
      gld_lds16(gBk + (size_t)row * rowb + ch * 16,
                (char*)Bs + (i * 256 + (w << 6)) * 16);
    }
    __syncthreads();
#pragma unroll
    for (int c = 0; c < 2; ++c) {
      bf16x8 af[4], bfr[2];
#pragma unroll
      for (int mi = 0; mi < 4; ++mi) {
        int row = wm * 64 + mi * 16 + l15;
        int ch = (c * 4 + l4) ^ (row & 7);
        af[mi] = *(const bf16x8*)(As + row * 64 + ch * 8);
      }
#pragma unroll
      for (int ni = 0; ni < 2; ++ni) {
        int row = wn * 32 + ni * 16 + l15;
        int ch = (c * 4 + l4) ^ (row & 7);
        bfr[ni] = *(const bf16x8*)(Bs + row * 64 + ch * 8);
      }
#pragma unroll
      for (int mi = 0; mi < 4; ++mi)
#pragma unroll
        for (int ni = 0; ni < 2; ++ni)
          acc[mi][ni] = __builtin_amdgcn_mfma_f32_16x16x32_bf16(
              af[mi], bfr[ni], acc[mi][ni], 0, 0, 0);
    }
    __syncthreads();
  }
#pragma unroll
  for (int mi = 0; mi < 4; ++mi) {
    int rbase = m0 + wm * 64 + mi * 16 + l4 * 4;
#pragma unroll
    for (int ni = 0; ni < 2; ++ni) {
      int col = n0 + wn * 32 + ni * 16 + l15;
#pragma unroll
      for (int r = 0; r < 4; ++r)
        Cf[(size_t)(rbase + r) * N + col] = acc[mi][ni][r];
    }
  }
}

// ---------------- K2+K3: RoPE(q) + RoPE(k)/holo, region-dispatched ---------
__global__ __launch_bounds__(256) void rope_holo(
    const bf16* __restrict__ qkv, const int* __restrict__ pos,
    const float* __restrict__ ct, const float* __restrict__ st,
    const float* __restrict__ cdma, bf16* __restrict__ Qr,
    bf16* __restrict__ Kn, bf16* __restrict__ Vt) {
  const int bid = blockIdx.x, tid = threadIdx.x;
  if (bid < 1024) {
    const float SCQ = 0.0901684403f;  // (1/16) * log2(e)
    int idx = bid * 256 + tid;
    int ih = idx & 3, s = (idx >> 2) & 2047, h = (idx >> 13) & 15, b = idx >> 17;
    int p = pos[b * SEQ + s];
    size_t base = ((size_t)(b * SEQ + s)) * 3072 + h * 64 + ih * 8;
    bf16x8 xv = *(const bf16x8*)(qkv + base);
    bf16x8 yv = *(const bf16x8*)(qkv + base + 32);
    const float* ctp = ct + p * 32 + ih * 8;
    const float* stp = st + p * 32 + ih * 8;
    bf16x8 o0, o1;
#pragma unroll
    for (int e = 0; e < 8; ++e) {
      float x = (float)xv[e], y = (float)yv[e];
      float co = ctp[e], sn = stp[e];
      o0[e] = (bf16)((x * co - y * sn) * SCQ);
      o1[e] = (bf16)((y * co + x * sn) * SCQ);
    }
    size_t ob = ((size_t)((b * 16 + h) * SEQ + s)) * 64 + ih * 8;
    *(bf16x8*)(Qr + ob) = o0;
    *(bf16x8*)(Qr + ob + 32) = o1;
  } else {
    int idx = (bid - 1024) * 256 + tid;
    int ih = idx & 3, slot = (idx >> 2) & 511, h = (idx >> 11) & 15, b = idx >> 15;
    float SK[8] = {}, SK2[8] = {}, SV[8] = {}, SV2[8] = {};
#pragma unroll
    for (int f = 0; f < 4; ++f) {
      int s = slot * 4 + f;
      size_t base = ((size_t)(b * SEQ + s)) * 3072 + h * 64 + ih * 8;
      bf16x8 klo = *(const bf16x8*)(qkv + base + 1024);
      bf16x8 khi = *(const bf16x8*)(qkv + base + 1024 + 32);
      bf16x8 vlo = *(const bf16x8*)(qkv + base + 2048);
      bf16x8 vhi = *(const bf16x8*)(qkv + base + 2048 + 32);
      int p = pos[b * SEQ + s];
      const float* ctp = ct + p * 32 + ih * 8;
      const float* stp = st + p * 32 + ih * 8;
      const float* cdp = cdma + f * 64 + ih * 8;
#pragma unroll
      for (int e = 0; e < 8; ++e) {
        float cf = cdp[e];
        float kx = (float)klo[e], ky = (float)khi[e];
        float co = ctp[e], sn = stp[e];
        SK[e]  += (kx * co - ky * sn) * cf;
        SK2[e] += (ky * co + kx * sn) * cf;
        SV[e]  += (float)vlo[e] * cf;
        SV2[e] += (float)vhi[e] * cf;
      }
    }
    size_t hb = (size_t)(b * 16 + h);
#pragma unroll
    for (int f = 0; f < 4; ++f) {
      int s = slot * 4 + f;
      const float* cdp = cdma + f * 64 + ih * 8;
      bf16x8 k0, k1;
#pragma unroll
      for (int e = 0; e < 8; ++e) {
        k0[e] = (bf16)(SK[e] * cdp[e]);
        k1[e] = (bf16)(SK2[e] * cdp[e]);
      }
      size_t krow = (hb * SEQ + s) * 64;
      int ch0 = ih ^ (s & 7);
      int ch1 = (4 + ih) ^ (s & 7);
      *(bf16x8*)(Kn + krow + ch0 * 8) = k0;
      *(bf16x8*)(Kn + krow + ch1 * 8) = k1;
      int seg = s >> 6, cl = s & 63;
      size_t vcol = (size_t)(seg << 6) + (cl & 7);
#pragma unroll
      for (int e = 0; e < 8; ++e) {
        int i = ih * 8 + e;
        int vch = (cl >> 3) ^ (i & 7);
        Vt[(hb * 64 + i) * (size_t)SEQ + vcol + vch * 8] = (bf16)(SV[e] * cdp[e]);
        Vt[(hb * 64 + i + 32) * (size_t)SEQ + vcol + vch * 8] = (bf16)(SV2[e] * cdp[e]);
      }
    }
  }
}

// ---------------- K4: causal flash attention (R14-exact) -------------------
__global__ __launch_bounds__(256) void attn_fwd(
    const bf16* __restrict__ Qr, const bf16* __restrict__ Kn,
    const bf16* __restrict__ Vt, bf16* __restrict__ AO) {
  __shared__ __align__(16) bf16 Kt[2][128 * 64];
  __shared__ __align__(16) bf16 Vl[2][64 * 128];
  __shared__ __align__(16) bf16 Pt[4][16 * 128];
  const int L = ((blockIdx.x & 7) << 6) + (blockIdx.x >> 3);
  const int pq = L & 15, h = (L >> 4) & 15, b = L >> 8;
  const int tid = threadIdx.x, lane = tid & 63, w = tid >> 6;
  const int l15 = lane & 15, l4 = lane >> 4;
  const size_t hd = ((size_t)(b * 16 + h)) * SEQ * 64;
  const char* gK0 = (const char*)(Kn + hd);
  const char* gV0 = (const char*)(Vt + hd);
  char* pw = (char*)&Pt[w][0];

#pragma unroll 1
  for (int phase = 0; phase < 2; ++phase) {
    const int qt = phase ? (31 - pq) : pq;
    const int q0 = qt * 64;
    const int qg = q0 + w * 16 + l15;
    const int nt = (qt >> 1) + 1;

    const bf16* qb = Qr + hd + (size_t)qg * 64;
    bf16x8 qf0 = *(const bf16x8*)(qb + l4 * 8);
    bf16x8 qf1 = *(const bf16x8*)(qb + 32 + l4 * 8);

    f32x4 oacc[4] = {};
    float m = -1e30f, lsum = 0.0f;

#pragma unroll
    for (int i = 0; i < 4; ++i)
      gld_lds16(gK0 + (i * 256 + tid) * 16,
                (char*)Kt[0] + (i * 256 + (w << 6)) * 16);
#pragma unroll
    for (int i = 0; i < 4; ++i) {
      int idx = i * 256 + tid;
      int row = idx >> 4, ch = idx & 15;
      gld_lds16(gV0 + (size_t)row * (SEQ * 2) + ch * 16,
                (char*)Vl[0] + (i * 256 + (w << 6)) * 16);
    }

#pragma unroll 1
    for (int t = 0; t < nt; ++t) {
      const int cur = t & 1;
      if (t + 1 < nt) {
        const int tn = t + 1, sb = cur ^ 1;
#pragma unroll
        for (int i = 0; i < 4; ++i)
          gld_lds16(gK0 + (size_t)tn * 16384 + (i * 256 + tid) * 16,
                    (char*)Kt[sb] + (i * 256 + (w << 6)) * 16);
#pragma unroll
        for (int i = 0; i < 4; ++i) {
          int idx = i * 256 + tid;
          int row = idx >> 4, ch = idx & 15;
          gld_lds16(gV0 + (size_t)row * (SEQ * 2) + tn * 256 + ch * 16,
                    (char*)Vl[sb] + (i * 256 + (w << 6)) * 16);
        }
        asm volatile("s_waitcnt vmcnt(8)\ns_barrier" ::: "memory");
      } else {
        asm volatile("s_waitcnt vmcnt(0)\ns_barrier" ::: "memory");
      }

      const bf16* Ktc = Kt[cur];
      const bf16* Vlc = Vl[cur];
      const int kv0 = t * 128;
      const bool lastt = (t == nt - 1);

      f32x4 sacc[8] = {};
#pragma unroll
      for (int c = 0; c < 2; ++c) {
        bf16x8 qf = c ? qf1 : qf0;
#pragma unroll
        for (int nf = 0; nf < 8; ++nf) {
          int row = nf * 16 + l15;
          int ch = (c * 4 + l4) ^ (row & 7);
          bf16x8 kf = *(const bf16x8*)(Ktc + row * 64 + ch * 8);
          sacc[nf] = __builtin_amdgcn_mfma_f32_16x16x32_bf16(kf, qf, sacc[nf], 0, 0, 0);
        }
      }

      float px[4] = {-1e30f, -1e30f, -1e30f, -1e30f};
      if (lastt) {
#pragma unroll
        for (int nf = 0; nf < 8; ++nf)
#pragma unroll
          for (int r = 0; r < 4; ++r) {
            int kvg = kv0 + nf * 16 + l4 * 4 + r;
            float v = (kvg > qg) ? -1e30f : sacc[nf][r];
            sacc[nf][r] = v;
            px[nf & 3] = fmaxf(px[nf & 3], v);
          }
      } else {
#pragma unroll
        for (int nf = 0; nf < 8; ++nf)
#pragma unroll
          for (int r = 0; r < 4; ++r) px[nf & 3] = fmaxf(px[nf & 3], sacc[nf][r]);
      }
      float pmax = fmaxf(fmaxf(px[0], px[1]), fmaxf(px[2], px[3]));
      pmax = fmaxf(pmax, __shfl_xor(pmax, 16));
      pmax = fmaxf(pmax, __shfl_xor(pmax, 32));

      if (!__all(pmax <= m)) {
        float mn = fmaxf(m, pmax);
        float al = exp2f(m - mn);
        m = mn;
        lsum *= al;
#pragma unroll
        for (int df = 0; df < 4; ++df) oacc[df] *= al;
      }
      float rs4[4] = {0.f, 0.f, 0.f, 0.f};
#pragma unroll
      for (int nf = 0; nf < 8; ++nf)
#pragma unroll
        for (int r = 0; r < 4; ++r) {
          float e = exp2f(sacc[nf][r] - m);
          sacc[nf][r] = e;
          rs4[nf & 3] += e;
        }
      float rs = (rs4[0] + rs4[1]) + (rs4[2] + rs4[3]);
      rs += __shfl_xor(rs, 16);
      rs += __shfl_xor(rs, 32);
      lsum += rs;

#pragma unroll
      for (int nf = 0; nf < 8; ++nf) {
        u32x2 u;
        u.x = pack2bf(sacc[nf][0], sacc[nf][1]);
        u.y = pack2bf(sacc[nf][2], sacc[nf][3]);
        int boff = (l15 * 256 + nf * 32 + l4 * 8) ^ ((l15 & 7) << 4);
        *(u32x2*)(pw + boff) = u;
      }

#pragma unroll
      for (int c2 = 0; c2 < 4; ++c2) {
        int pb = (l15 * 256 + c2 * 64 + l4 * 16) ^ ((l15 & 7) << 4);
        bf16x8 pf = *(const bf16x8*)(pw + pb);
        int vbyte = (c2 * 64 + l4 * 16) ^ ((l15 & 7) << 4);
#pragma unroll
        for (int df = 0; df < 4; ++df) {
          int vrow = df * 16 + l15;
          bf16x8 vf = *(const bf16x8*)((const char*)Vlc + vrow * 256 + vbyte);
          oacc[df] = __builtin_amdgcn_mfma_f32_16x16x32_bf16(vf, pf, oacc[df], 0, 0, 0);
        }
      }
      asm volatile("s_barrier" ::: "memory");
    }

    // epilogue: O^T -> AO, b64 stores (d>>3 constant across r; d&7=(l4&1)*4+r)
    const float li = 1.0f / lsum;
    const size_t arow = ((size_t)(b * SEQ + qg)) * HID + h * 64;
    const int qk7 = qg & 7;
#pragma unroll
    for (int df = 0; df < 4; ++df) {
      int ch = (df * 2 + (l4 >> 1)) ^ qk7;
      u32x2 u;
      u.x = pack2bf(oacc[df][0] * li, oacc[df][1] * li);
      u.y = pack2bf(oacc[df][2] * li, oacc[df][3] * li);
      *(u32x2*)(AO + arow + ch * 8 + (l4 & 1) * 4) = u;
    }
  }
}

// ---------------------------------------------------------------------------
extern "C" void kernel_launch(void* const* d_in, const int* in_sizes, int n_in,
                              void* d_out, int out_size, void* d_ws, size_t ws_size,
                              hipStream_t stream) {
  const float* hs  = (const float*)d_in[0];
  const int* pos   = (const int*)d_in[1];
  const float* qw  = (const float*)d_in[2];
  const float* qb_ = (const float*)d_in[3];
  const float* kw  = (const float*)d_in[4];
  const float* kb_ = (const float*)d_in[5];
  const float* vw  = (const float*)d_in[6];
  const float* vb_ = (const float*)d_in[7];
  const float* ow  = (const float*)d_in[8];
  const float* qA  = (const float*)d_in[9];
  const float* qB  = (const float*)d_in[10];
  const float* vA  = (const float*)d_in[11];
  const float* vB  = (const float*)d_in[12];
  const float* cd  = (const float*)d_in[13];

  char* p = (char*)d_ws;
  auto alloc = [&](size_t bytes) {
    char* r = p; p += (bytes + 255) & ~(size_t)255; return r;
  };
  bf16* hsb   = (bf16*)alloc((size_t)4096 * 1024 * 2);
  bf16* Wqkv  = (bf16*)alloc((size_t)3072 * 1024 * 2);
  float* bqkv = (float*)alloc(3072 * 4);
  bf16* owb   = (bf16*)alloc((size_t)1024 * 1024 * 2);
  bf16* qkvb  = (bf16*)alloc((size_t)4096 * 3072 * 2);
  float* ct   = (float*)alloc((size_t)SEQ * 32 * 4);
  float* st   = (float*)alloc((size_t)SEQ * 32 * 4);
  bf16* Qrb   = (bf16*)alloc((size_t)NB * NHD * SEQ * 64 * 2);
  bf16* Knb   = (bf16*)alloc((size_t)NB * NHD * SEQ * 64 * 2);
  bf16* Vtb   = (bf16*)alloc((size_t)NB * NHD * 64 * SEQ * 2);
  bf16* AOb   = (bf16*)alloc((size_t)4096 * 1024 * 2);

  prep_all<<<dim3(PB_TAB), 256, 0, stream>>>(
      hs, ow, qw, qb_, kw, kb_, vw, vb_, qA, qB, vA, vB,
      hsb, owb, Wqkv, bqkv, ct, st);
  gemm_bt<<<dim3(3072 / 128, 4096 / 128), 256, 0, stream>>>(
      hsb, Wqkv, bqkv, qkvb, nullptr, 4096, 3072, 1024);
  rope_holo<<<dim3(1024 + 256), 256, 0, stream>>>(
      qkvb, pos, ct, st, cd, Qrb, Knb, Vtb);
  attn_fwd<<<dim3(512), 256, 0, stream>>>(Qrb, Knb, Vtb, AOb);
  gemm_bt_n64<<<dim3(1024 / 64, 4096 / 128), 256, 0, stream>>>(
      AOb, owb, (float*)d_out, 4096, 1024, 1024);
}

// Round 21
// 144.083 us; speedup vs baseline: 1.1289x; 1.0028x over previous
//
#include <hip/hip_runtime.h>
#include <hip/hip_bf16.h>
#include <math.h>

// ---------------------------------------------------------------------------
// HoloKVSimulatorLayer fused pipeline, bf16 MFMA, MI355X (gfx950)
//   B=2 S=2048 H=1024 NH=NKV=16 HD=64 R=16 KF=4 theta=1e6
// R18: gemm1 XCD-aware block remap (1-D grid 768; each XCD owns 3 n-tiles ->
// B-panels L2-resident, A streams once). Everything else = R17.
// ---------------------------------------------------------------------------

typedef __bf16 bf16;
typedef __attribute__((ext_vector_type(8))) __bf16 bf16x8;
typedef __attribute__((ext_vector_type(4))) float f32x4;
typedef __attribute__((ext_vector_type(2))) unsigned u32x2;

#define NB 2
#define SEQ 2048
#define HID 1024
#define NHD 16
#define HDD 64

__device__ __forceinline__ void gld_lds16(const void* g, void* l) {
  __builtin_amdgcn_global_load_lds(
      (const __attribute__((address_space(1))) void*)g,
      (__attribute__((address_space(3))) void*)l, 16, 0, 0);
}

__device__ __forceinline__ unsigned pack2bf(float a, float b) {
  unsigned short ua = __builtin_bit_cast(unsigned short, (bf16)a);
  unsigned short ub = __builtin_bit_cast(unsigned short, (bf16)b);
  return ((unsigned)ub << 16) | ua;
}

// ---------------- P*: all preprocessing, vectorized (4 f32/thread) ---------
#define PB_W    3072
#define PB_HS   (PB_W + 4096)
#define PB_OW   (PB_HS + 1024)
#define PB_BIAS (PB_OW + 12)
#define PB_TAB  (PB_BIAS + 256)

__global__ __launch_bounds__(256) void prep_all(
    const float* __restrict__ hs, const float* __restrict__ ow,
    const float* __restrict__ qw, const float* __restrict__ qb,
    const float* __restrict__ kw, const float* __restrict__ kb,
    const float* __restrict__ vw, const float* __restrict__ vb,
    const float* __restrict__ qA, const float* __restrict__ qB,
    const float* __restrict__ vA, const float* __restrict__ vB,
    bf16* __restrict__ hsb, bf16* __restrict__ owb, bf16* __restrict__ Wqkv,
    float* __restrict__ bqkv, float* __restrict__ ct, float* __restrict__ st) {
  const int bid = blockIdx.x, tid = threadIdx.x;
  if (bid < PB_W) {
    int idx = bid * 256 + tid;           // n*256 + k4idx, n in [0,3072)
    int n = idx >> 8, k4 = (idx & 255) << 2;
    f32x4 v;
    if (n < 1024) {
      v = *(const f32x4*)(qw + (size_t)n * 1024 + k4);
#pragma unroll
      for (int r = 0; r < 16; ++r) {
        float bq = qB[n * 16 + r];
        f32x4 a = *(const f32x4*)(qA + (size_t)r * 1024 + k4);
        v.x += bq * a.x; v.y += bq * a.y; v.z += bq * a.z; v.w += bq * a.w;
      }
    } else if (n < 2048) {
      v = *(const f32x4*)(kw + (size_t)(n - 1024) * 1024 + k4);
    } else {
      int nn = n - 2048;
      v = *(const f32x4*)(vw + (size_t)nn * 1024 + k4);
#pragma unroll
      for (int r = 0; r < 16; ++r) {
        float bv = vB[nn * 16 + r];
        f32x4 a = *(const f32x4*)(vA + (size_t)r * 1024 + k4);
        v.x += bv * a.x; v.y += bv * a.y; v.z += bv * a.z; v.w += bv * a.w;
      }
    }
    int seg = k4 >> 6, cl = k4 & 63;
    int ch = (cl >> 3) ^ (n & 7);
    u32x2 u; u.x = pack2bf(v.x, v.y); u.y = pack2bf(v.z, v.w);
    *(u32x2*)(Wqkv + (size_t)n * 1024 + (seg << 6) + (ch << 3) + (cl & 7)) = u;
  } else if (bid < PB_HS) {
    int idx = (bid - PB_W) * 256 + tid;  // r*256 + c4idx
    int r = idx >> 8, c4 = (idx & 255) << 2;
    f32x4 v = *(const f32x4*)(hs + (size_t)r * 1024 + c4);
    int seg = c4 >> 6, cl = c4 & 63;
    int ch = (cl >> 3) ^ (r & 7);
    u32x2 u; u.x = pack2bf(v.x, v.y); u.y = pack2bf(v.z, v.w);
    *(u32x2*)(hsb + (size_t)r * 1024 + (seg << 6) + (ch << 3) + (cl & 7)) = u;
  } else if (bid < PB_OW) {
    int idx = (bid - PB_HS) * 256 + tid;
    int r = idx >> 8, c4 = (idx & 255) << 2;
    f32x4 v = *(const f32x4*)(ow + (size_t)r * 1024 + c4);
    int seg = c4 >> 6, cl = c4 & 63;
    int ch = (cl >> 3) ^ (r & 7);
    u32x2 u; u.x = pack2bf(v.x, v.y); u.y = pack2bf(v.z, v.w);
    *(u32x2*)(owb + (size_t)r * 1024 + (seg << 6) + (ch << 3) + (cl & 7)) = u;
  } else if (bid < PB_BIAS) {
    int i = (bid - PB_OW) * 256 + tid;
    if (i < 3072)
      bqkv[i] = (i < 1024) ? qb[i] : (i < 2048 ? kb[i - 1024] : vb[i - 2048]);
  } else {
    int idx = (bid - PB_BIAS) * 256 + tid;  // s*32 + i
    int s = idx >> 5, i = idx & 31;
    double inv = pow(1.0e6, -(double)i / 32.0);
    double a = (double)s * inv;
    ct[idx] = (float)cos(a);
    st[idx] = (float)sin(a);
  }
}

// ---------------- K1: bf16 MFMA GEMM 128x128, XCD-clustered ----------------
// 1-D grid 768. xcd=bid&7 owns n-tiles {3*xcd..3*xcd+2}: B-panels (0.75MB)
// stay L2-resident across all 32 m-tiles; A streams once via L3.
__global__ __launch_bounds__(256, 4) void gemm_bt(
    const bf16* __restrict__ A, const bf16* __restrict__ Bw,
    const float* __restrict__ bias, bf16* __restrict__ Cb,
    float* __restrict__ Cf, int M, int N, int K) {
  __shared__ __align__(16) bf16 As[128 * 64];
  __shared__ __align__(16) bf16 Bs[128 * 64];
  const int bid = blockIdx.x;
  const int xcd = bid & 7, li = bid >> 3;
  const int m0 = (li / 3) * 128, n0 = (xcd * 3 + li % 3) * 128;
  const int tid = threadIdx.x;
  const int lane = tid & 63, w = tid >> 6;
  const int wm = w >> 1, wn = w & 1;
  const int l15 = lane & 15, l4 = lane >> 4;
  const size_t rowb = (size_t)K * 2;
  const char* gA = (const char*)A + (size_t)m0 * rowb;
  const char* gB = (const char*)Bw + (size_t)n0 * rowb;
  f32x4 acc[4][4] = {};

  for (int k0 = 0; k0 < K; k0 += 64) {
    const char* gAk = gA + k0 * 2;
    const char* gBk = gB + k0 * 2;
#pragma unroll
    for (int i = 0; i < 4; ++i) {
      int idx = i * 256 + tid;
      int row = idx >> 3, ch = idx & 7;
      gld_lds16(gAk + (size_t)row * rowb + ch * 16,
                (char*)As + (i * 256 + (w << 6)) * 16);
      gld_lds16(gBk + (size_t)row * rowb + ch * 16,
                (char*)Bs + (i * 256 + (w << 6)) * 16);
    }
    __syncthreads();
#pragma unroll
    for (int c = 0; c < 2; ++c) {
      bf16x8 af[4], bfr[4];
#pragma unroll
      for (int mi = 0; mi < 4; ++mi) {
        int row = wm * 64 + mi * 16 + l15;
        int ch = (c * 4 + l4) ^ (row & 7);
        af[mi] = *(const bf16x8*)(As + row * 64 + ch * 8);
      }
#pragma unroll
      for (int ni = 0; ni < 4; ++ni) {
        int row = wn * 64 + ni * 16 + l15;
        int ch = (c * 4 + l4) ^ (row & 7);
        bfr[ni] = *(const bf16x8*)(Bs + row * 64 + ch * 8);
      }
#pragma unroll
      for (int mi = 0; mi < 4; ++mi)
#pragma unroll
        for (int ni = 0; ni < 4; ++ni)
          acc[mi][ni] = __builtin_amdgcn_mfma_f32_16x16x32_bf16(
              af[mi], bfr[ni], acc[mi][ni], 0, 0, 0);
    }
    __syncthreads();
  }
#pragma unroll
  for (int mi = 0; mi < 4; ++mi) {
    int rbase = m0 + wm * 64 + mi * 16 + l4 * 4;
#pragma unroll
    for (int ni = 0; ni < 4; ++ni) {
      int col = n0 + wn * 64 + ni * 16 + l15;
      float badd = bias ? bias[col] : 0.0f;
#pragma unroll
      for (int r = 0; r < 4; ++r) {
        float v = acc[mi][ni][r] + badd;
        if (Cf) Cf[(size_t)(rbase + r) * N + col] = v;
        else    Cb[(size_t)(rbase + r) * N + col] = (bf16)v;
      }
    }
  }
}

// ---------------- K5: bf16 MFMA GEMM 128x64 (f32 out), 2 blocks/CU ---------
__global__ __launch_bounds__(256, 4) void gemm_bt_n64(
    const bf16* __restrict__ A, const bf16* __restrict__ Bw,
    float* __restrict__ Cf, int M, int N, int K) {
  __shared__ __align__(16) bf16 As[128 * 64];
  __shared__ __align__(16) bf16 Bs[64 * 64];
  const int tid = threadIdx.x;
  const int lane = tid & 63, w = tid >> 6;
  const int wm = w >> 1, wn = w & 1;
  const int l15 = lane & 15, l4 = lane >> 4;
  const int m0 = blockIdx.y * 128, n0 = blockIdx.x * 64;
  const size_t rowb = (size_t)K * 2;
  const char* gA = (const char*)A + (size_t)m0 * rowb;
  const char* gB = (const char*)Bw + (size_t)n0 * rowb;
  f32x4 acc[4][2] = {};

  for (int k0 = 0; k0 < K; k0 += 64) {
    const char* gAk = gA + k0 * 2;
    const char* gBk = gB + k0 * 2;
#pragma unroll
    for (int i = 0; i < 4; ++i) {
      int idx = i * 256 + tid;
      int row = idx >> 3, ch = idx & 7;
      gld_lds16(gAk + (size_t)row * rowb + ch * 16,
                (char*)As + (i * 256 + (w << 6)) * 16);
    }
#pragma unroll
    for (int i = 0; i < 2; ++i) {
      int idx = i * 256 + tid;
      int row = idx >> 3, ch = idx & 7;
      gld_lds16(gBk + (size_t)row * rowb + ch * 16,
                (char*)Bs + (i * 256 + (w << 6)) * 16);
    }
    __syncthreads();
#pragma unroll
    for (int c = 0; c < 2; ++c) {
      bf16x8 af[4], bfr[2];
#pragma unroll
      for (int mi = 0; mi < 4; ++mi) {
        int row = wm * 64 + mi * 16 + l15;
        int ch = (c * 4 + l4) ^ (row & 7);
        af[mi] = *(const bf16x8*)(As + row * 64 + ch * 8);
      }
#pragma unroll
      for (int ni = 0; ni < 2; ++ni) {
        int row = wn * 32 + ni * 16 + l15;
        int ch = (c * 4 + l4) ^ (row & 7);
        bfr[ni] = *(const bf16x8*)(Bs + row * 64 + ch * 8);
      }
#pragma unroll
      for (int mi = 0; mi < 4; ++mi)
#pragma unroll
        for (int ni = 0; ni < 2; ++ni)
          acc[mi][ni] = __builtin_amdgcn_mfma_f32_16x16x32_bf16(
              af[mi], bfr[ni], acc[mi][ni], 0, 0, 0);
    }
    __syncthreads();
  }
#pragma unroll
  for (int mi = 0; mi < 4; ++mi) {
    int rbase = m0 + wm * 64 + mi * 16 + l4 * 4;
#pragma unroll
    for (int ni = 0; ni < 2; ++ni) {
      int col = n0 + wn * 32 + ni * 16 + l15;
#pragma unroll
      for (int r = 0; r < 4; ++r)
        Cf[(size_t)(rbase + r) * N + col] = acc[mi][ni][r];
    }
  }
}

// ---------------- K2+K3: RoPE(q) + RoPE(k)/holo, region-dispatched ---------
__global__ __launch_bounds__(256) void rope_holo(
    const bf16* __restrict__ qkv, const int* __restrict__ pos,
    const float* __restrict__ ct, const float* __restrict__ st,
    const float* __restrict__ cdma, bf16* __restrict__ Qr,
    bf16* __restrict__ Kn, bf16* __restrict__ Vt) {
  const int bid = blockIdx.x, tid = threadIdx.x;
  if (bid < 1024) {
    const float SCQ = 0.0901684403f;  // (1/16) * log2(e)
    int idx = bid * 256 + tid;
    int ih = idx & 3, s = (idx >> 2) & 2047, h = (idx >> 13) & 15, b = idx >> 17;
    int p = pos[b * SEQ + s];
    size_t base = ((size_t)(b * SEQ + s)) * 3072 + h * 64 + ih * 8;
    bf16x8 xv = *(const bf16x8*)(qkv + base);
    bf16x8 yv = *(const bf16x8*)(qkv + base + 32);
    const float* ctp = ct + p * 32 + ih * 8;
    const float* stp = st + p * 32 + ih * 8;
    bf16x8 o0, o1;
#pragma unroll
    for (int e = 0; e < 8; ++e) {
      float x = (float)xv[e], y = (float)yv[e];
      float co = ctp[e], sn = stp[e];
      o0[e] = (bf16)((x * co - y * sn) * SCQ);
      o1[e] = (bf16)((y * co + x * sn) * SCQ);
    }
    size_t ob = ((size_t)((b * 16 + h) * SEQ + s)) * 64 + ih * 8;
    *(bf16x8*)(Qr + ob) = o0;
    *(bf16x8*)(Qr + ob + 32) = o1;
  } else {
    int idx = (bid - 1024) * 256 + tid;
    int ih = idx & 3, slot = (idx >> 2) & 511, h = (idx >> 11) & 15, b = idx >> 15;
    float SK[8] = {}, SK2[8] = {}, SV[8] = {}, SV2[8] = {};
#pragma unroll
    for (int f = 0; f < 4; ++f) {
      int s = slot * 4 + f;
      size_t base = ((size_t)(b * SEQ + s)) * 3072 + h * 64 + ih * 8;
      bf16x8 klo = *(const bf16x8*)(qkv + base + 1024);
      bf16x8 khi = *(const bf16x8*)(qkv + base + 1024 + 32);
      bf16x8 vlo = *(const bf16x8*)(qkv + base + 2048);
      bf16x8 vhi = *(const bf16x8*)(qkv + base + 2048 + 32);
      int p = pos[b * SEQ + s];
      const float* ctp = ct + p * 32 + ih * 8;
      const float* stp = st + p * 32 + ih * 8;
      const float* cdp = cdma + f * 64 + ih * 8;
#pragma unroll
      for (int e = 0; e < 8; ++e) {
        float cf = cdp[e];
        float kx = (float)klo[e], ky = (float)khi[e];
        float co = ctp[e], sn = stp[e];
        SK[e]  += (kx * co - ky * sn) * cf;
        SK2[e] += (ky * co + kx * sn) * cf;
        SV[e]  += (float)vlo[e] * cf;
        SV2[e] += (float)vhi[e] * cf;
      }
    }
    size_t hb = (size_t)(b * 16 + h);
#pragma unroll
    for (int f = 0; f < 4; ++f) {
      int s = slot * 4 + f;
      const float* cdp = cdma + f * 64 + ih * 8;
      bf16x8 k0, k1;
#pragma unroll
      for (int e = 0; e < 8; ++e) {
        k0[e] = (bf16)(SK[e] * cdp[e]);
        k1[e] = (bf16)(SK2[e] * cdp[e]);
      }
      size_t krow = (hb * SEQ + s) * 64;
      int ch0 = ih ^ (s & 7);
      int ch1 = (4 + ih) ^ (s & 7);
      *(bf16x8*)(Kn + krow + ch0 * 8) = k0;
      *(bf16x8*)(Kn + krow + ch1 * 8) = k1;
      int seg = s >> 6, cl = s & 63;
      size_t vcol = (size_t)(seg << 6) + (cl & 7);
#pragma unroll
      for (int e = 0; e < 8; ++e) {
        int i = ih * 8 + e;
        int vch = (cl >> 3) ^ (i & 7);
        Vt[(hb * 64 + i) * (size_t)SEQ + vcol + vch * 8] = (bf16)(SV[e] * cdp[e]);
        Vt[(hb * 64 + i + 32) * (size_t)SEQ + vcol + vch * 8] = (bf16)(SV2[e] * cdp[e]);
      }
    }
  }
}

// ---------------- K4: causal flash attention (R14-exact) -------------------
__global__ __launch_bounds__(256) void attn_fwd(
    const bf16* __restrict__ Qr, const bf16* __restrict__ Kn,
    const bf16* __restrict__ Vt, bf16* __restrict__ AO) {
  __shared__ __align__(16) bf16 Kt[2][128 * 64];
  __shared__ __align__(16) bf16 Vl[2][64 * 128];
  __shared__ __align__(16) bf16 Pt[4][16 * 128];
  const int L = ((blockIdx.x & 7) << 6) + (blockIdx.x >> 3);
  const int pq = L & 15, h = (L >> 4) & 15, b = L >> 8;
  const int tid = threadIdx.x, lane = tid & 63, w = tid >> 6;
  const int l15 = lane & 15, l4 = lane >> 4;
  const size_t hd = ((size_t)(b * 16 + h)) * SEQ * 64;
  const char* gK0 = (const char*)(Kn + hd);
  const char* gV0 = (const char*)(Vt + hd);
  char* pw = (char*)&Pt[w][0];

#pragma unroll 1
  for (int phase = 0; phase < 2; ++phase) {
    const int qt = phase ? (31 - pq) : pq;
    const int q0 = qt * 64;
    const int qg = q0 + w * 16 + l15;
    const int nt = (qt >> 1) + 1;

    const bf16* qb = Qr + hd + (size_t)qg * 64;
    bf16x8 qf0 = *(const bf16x8*)(qb + l4 * 8);
    bf16x8 qf1 = *(const bf16x8*)(qb + 32 + l4 * 8);

    f32x4 oacc[4] = {};
    float m = -1e30f, lsum = 0.0f;

#pragma unroll
    for (int i = 0; i < 4; ++i)
      gld_lds16(gK0 + (i * 256 + tid) * 16,
                (char*)Kt[0] + (i * 256 + (w << 6)) * 16);
#pragma unroll
    for (int i = 0; i < 4; ++i) {
      int idx = i * 256 + tid;
      int row = idx >> 4, ch = idx & 15;
      gld_lds16(gV0 + (size_t)row * (SEQ * 2) + ch * 16,
                (char*)Vl[0] + (i * 256 + (w << 6)) * 16);
    }

#pragma unroll 1
    for (int t = 0; t < nt; ++t) {
      const int cur = t & 1;
      if (t + 1 < nt) {
        const int tn = t + 1, sb = cur ^ 1;
#pragma unroll
        for (int i = 0; i < 4; ++i)
          gld_lds16(gK0 + (size_t)tn * 16384 + (i * 256 + tid) * 16,
                    (char*)Kt[sb] + (i * 256 + (w << 6)) * 16);
#pragma unroll
        for (int i = 0; i < 4; ++i) {
          int idx = i * 256 + tid;
          int row = idx >> 4, ch = idx & 15;
          gld_lds16(gV0 + (size_t)row * (SEQ * 2) + tn * 256 + ch * 16,
                    (char*)Vl[sb] + (i * 256 + (w << 6)) * 16);
        }
        asm volatile("s_waitcnt vmcnt(8)\ns_barrier" ::: "memory");
      } else {
        asm volatile("s_waitcnt vmcnt(0)\ns_barrier" ::: "memory");
      }

      const bf16* Ktc = Kt[cur];
      const bf16* Vlc = Vl[cur];
      const int kv0 = t * 128;
      const bool lastt = (t == nt - 1);

      f32x4 sacc[8] = {};
#pragma unroll
      for (int c = 0; c < 2; ++c) {
        bf16x8 qf = c ? qf1 : qf0;
#pragma unroll
        for (int nf = 0; nf < 8; ++nf) {
          int row = nf * 16 + l15;
          int ch = (c * 4 + l4) ^ (row & 7);
          bf16x8 kf = *(const bf16x8*)(Ktc + row * 64 + ch * 8);
          sacc[nf] = __builtin_amdgcn_mfma_f32_16x16x32_bf16(kf, qf, sacc[nf], 0, 0, 0);
        }
      }

      float px[4] = {-1e30f, -1e30f, -1e30f, -1e30f};
      if (lastt) {
#pragma unroll
        for (int nf = 0; nf < 8; ++nf)
#pragma unroll
          for (int r = 0; r < 4; ++r) {
            int kvg = kv0 + nf * 16 + l4 * 4 + r;
            float v = (kvg > qg) ? -1e30f : sacc[nf][r];
            sacc[nf][r] = v;
            px[nf & 3] = fmaxf(px[nf & 3], v);
          }
      } else {
#pragma unroll
        for (int nf = 0; nf < 8; ++nf)
#pragma unroll
          for (int r = 0; r < 4; ++r) px[nf & 3] = fmaxf(px[nf & 3], sacc[nf][r]);
      }
      float pmax = fmaxf(fmaxf(px[0], px[1]), fmaxf(px[2], px[3]));
      pmax = fmaxf(pmax, __shfl_xor(pmax, 16));
      pmax = fmaxf(pmax, __shfl_xor(pmax, 32));

      if (!__all(pmax <= m)) {
        float mn = fmaxf(m, pmax);
        float al = exp2f(m - mn);
        m = mn;
        lsum *= al;
#pragma unroll
        for (int df = 0; df < 4; ++df) oacc[df] *= al;
      }
      float rs4[4] = {0.f, 0.f, 0.f, 0.f};
#pragma unroll
      for (int nf = 0; nf < 8; ++nf)
#pragma unroll
        for (int r = 0; r < 4; ++r) {
          float e = exp2f(sacc[nf][r] - m);
          sacc[nf][r] = e;
          rs4[nf & 3] += e;
        }
      float rs = (rs4[0] + rs4[1]) + (rs4[2] + rs4[3]);
      rs += __shfl_xor(rs, 16);
      rs += __shfl_xor(rs, 32);
      lsum += rs;

#pragma unroll
      for (int nf = 0; nf < 8; ++nf) {
        u32x2 u;
        u.x = pack2bf(sacc[nf][0], sacc[nf][1]);
        u.y = pack2bf(sacc[nf][2], sacc[nf][3]);
        int boff = (l15 * 256 + nf * 32 + l4 * 8) ^ ((l15 & 7) << 4);
        *(u32x2*)(pw + boff) = u;
      }

#pragma unroll
      for (int c2 = 0; c2 < 4; ++c2) {
        int pb = (l15 * 256 + c2 * 64 + l4 * 16) ^ ((l15 & 7) << 4);
        bf16x8 pf = *(const bf16x8*)(pw + pb);
        int vbyte = (c2 * 64 + l4 * 16) ^ ((l15 & 7) << 4);
#pragma unroll
        for (int df = 0; df < 4; ++df) {
          int vrow = df * 16 + l15;
          bf16x8 vf = *(const bf16x8*)((const char*)Vlc + vrow * 256 + vbyte);
          oacc[df] = __builtin_amdgcn_mfma_f32_16x16x32_bf16(vf, pf, oacc[df], 0, 0, 0);
        }
      }
      asm volatile("s_barrier" ::: "memory");
    }

    // epilogue: O^T -> AO, b64 stores (d>>3 constant across r; d&7=(l4&1)*4+r)
    const float li = 1.0f / lsum;
    const size_t arow = ((size_t)(b * SEQ + qg)) * HID + h * 64;
    const int qk7 = qg & 7;
#pragma unroll
    for (int df = 0; df < 4; ++df) {
      int ch = (df * 2 + (l4 >> 1)) ^ qk7;
      u32x2 u;
      u.x = pack2bf(oacc[df][0] * li, oacc[df][1] * li);
      u.y = pack2bf(oacc[df][2] * li, oacc[df][3] * li);
      *(u32x2*)(AO + arow + ch * 8 + (l4 & 1) * 4) = u;
    }
  }
}

// ---------------------------------------------------------------------------
extern "C" void kernel_launch(void* const* d_in, const int* in_sizes, int n_in,
                              void* d_out, int out_size, void* d_ws, size_t ws_size,
                              hipStream_t stream) {
  const float* hs  = (const float*)d_in[0];
  const int* pos   = (const int*)d_in[1];
  const float* qw  = (const float*)d_in[2];
  const float* qb_ = (const float*)d_in[3];
  const float* kw  = (const float*)d_in[4];
  const float* kb_ = (const float*)d_in[5];
  const float* vw  = (const float*)d_in[6];
  const float* vb_ = (const float*)d_in[7];
  const float* ow  = (const float*)d_in[8];
  const float* qA  = (const float*)d_in[9];
  const float* qB  = (const float*)d_in[10];
  const float* vA  = (const float*)d_in[11];
  const float* vB  = (const float*)d_in[12];
  const float* cd  = (const float*)d_in[13];

  char* p = (char*)d_ws;
  auto alloc = [&](size_t bytes) {
    char* r = p; p += (bytes + 255) & ~(size_t)255; return r;
  };
  bf16* hsb   = (bf16*)alloc((size_t)4096 * 1024 * 2);
  bf16* Wqkv  = (bf16*)alloc((size_t)3072 * 1024 * 2);
  float* bqkv = (float*)alloc(3072 * 4);
  bf16* owb   = (bf16*)alloc((size_t)1024 * 1024 * 2);
  bf16* qkvb  = (bf16*)alloc((size_t)4096 * 3072 * 2);
  float* ct   = (float*)alloc((size_t)SEQ * 32 * 4);
  float* st   = (float*)alloc((size_t)SEQ * 32 * 4);
  bf16* Qrb   = (bf16*)alloc((size_t)NB * NHD * SEQ * 64 * 2);
  bf16* Knb   = (bf16*)alloc((size_t)NB * NHD * SEQ * 64 * 2);
  bf16* Vtb   = (bf16*)alloc((size_t)NB * NHD * 64 * SEQ * 2);
  bf16* AOb   = (bf16*)alloc((size_t)4096 * 1024 * 2);

  prep_all<<<dim3(PB_TAB), 256, 0, stream>>>(
      hs, ow, qw, qb_, kw, kb_, vw, vb_, qA, qB, vA, vB,
      hsb, owb, Wqkv, bqkv, ct, st);
  gemm_bt<<<dim3(768), 256, 0, stream>>>(
      hsb, Wqkv, bqkv, qkvb, nullptr, 4096, 3072, 1024);
  rope_holo<<<dim3(1024 + 256), 256, 0, stream>>>(
      qkvb, pos, ct, st, cd, Qrb, Knb, Vtb);
  attn_fwd<<<dim3(512), 256, 0, stream>>>(Qrb, Knb, Vtb, AOb);
  gemm_bt_n64<<<dim3(1024 / 64, 4096 / 128), 256, 0, stream>>>(
      AOb, owb, (float*)d_out, 4096, 1024, 1024);
}